// Round 5
// baseline (564.313 us; speedup 1.0000x reference)
//
#include <hip/hip_runtime.h>

#define N_PRE 1024
#define N_POST 2048
#define SEQ_LEN 4096

// Reference-verified numerics (R11 PASS): per C element two fp32 segment
// chains k in [0,512) and [512,1024), ascending, single accumulator each,
// combined rn(S1+S2). stim in {0,1} -> products exact -> FMA == mul+add.
// Scan: v = rn(rn(v*0.9f) + c), fire >= 1.0f, reset 0. DO NOT REORDER.
//
// v6 (sparse): skipping adds of exact +/-0.0 is BIT-IDENTICAL (acc starts
// +0.0 and RN never produces -0.0 from a sum; rn(acc + ±0) == acc).  So we
// walk the ascending per-t spike list, lo-chain for k<512, hi-chain for
// k>=512, write rn(lo+hi).  Same values, ~10% of the adds.
#define KSPLIT 512

__device__ __forceinline__ float opaque(float x) {
  asm volatile("" : "+v"(x));
  return x;
}

__device__ __forceinline__ float load_dyn(const void* p, size_t idx, bool isbf) {
  if (isbf) {
    const unsigned short b = ((const unsigned short*)p)[idx];
    return __uint_as_float(((unsigned int)b) << 16);
  }
  return ((const float*)p)[idx];
}

// Input-dtype sniff (established: weights fp32, stim bf16; kept for safety).
__device__ __forceinline__ int sniff_flags(const void* W, const void* S, int tid,
                                           int* flags_sh) {
  if (tid < 64) {
    const unsigned short* uw = (const unsigned short*)W;
    const float f = fabsf(__uint_as_float(((unsigned int)uw[tid * 2]) << 16));
    const bool big = !(f < 64.f);
    const unsigned long long wb = __ballot(big);
    const unsigned short* us = (const unsigned short*)S;
    int hit = 0;
    for (int j = 0; j < 64; ++j) hit |= (us[tid * 128 + 2 * j] == 0x3F80u) ? 1 : 0;
    const unsigned long long sb = __ballot(hit != 0);
    if (tid == 0) *flags_sh = ((wb == 0ull) ? 1 : 0) | ((sb != 0ull) ? 2 : 0);
  }
  __syncthreads();
  return *flags_sh;
}

// ---------------- WT build: W[n][k] -> WT[k][n] (fp32), LDS transpose -------
__global__ __launch_bounds__(256) void snn_wt_build(const void* __restrict__ W,
                                                    const void* __restrict__ S,
                                                    float* __restrict__ WT) {
  __shared__ float tile[64][65];  // [k][n], 65-pad: banks (k + n) mod 32
  __shared__ int flags_sh;
  const int tid = threadIdx.x;
  const int fl = sniff_flags(W, S, tid, &flags_sh);
  const bool w_bf = (fl & 1) != 0;
  const int k0 = blockIdx.x * 64;
  const int nn0 = blockIdx.y * 64;
  {
    const int r = tid >> 2;        // n row 0..63
    const int cq = tid & 3;        // k quarter
    if (!w_bf) {
      const float* Wf = (const float*)W;
#pragma unroll
      for (int p = 0; p < 4; ++p) {
        const int c = cq * 16 + p * 4;
        const float4 va = *(const float4*)&Wf[(size_t)(nn0 + r) * N_PRE + k0 + c];
        tile[c + 0][r] = va.x; tile[c + 1][r] = va.y;
        tile[c + 2][r] = va.z; tile[c + 3][r] = va.w;
      }
    } else {
#pragma unroll
      for (int p = 0; p < 4; ++p)
#pragma unroll
        for (int j = 0; j < 4; ++j) {
          const int c = cq * 16 + p * 4 + j;
          tile[c][r] = load_dyn(W, (size_t)(nn0 + r) * N_PRE + k0 + c, true);
        }
    }
  }
  __syncthreads();
  {
    const int kr = tid >> 2;  // k row 0..63
    const int nq = tid & 3;   // n quarter
#pragma unroll
    for (int p = 0; p < 4; ++p) {
      const int c = nq * 16 + p * 4;
      float4 o;
      o.x = tile[kr][c + 0]; o.y = tile[kr][c + 1];
      o.z = tile[kr][c + 2]; o.w = tile[kr][c + 3];
      *(float4*)&WT[(size_t)(k0 + kr) * N_POST + nn0 + c] = o;
    }
  }
}

// ---------------- mask build: stim -> MT[t/8][k] bitmask bytes --------------
__global__ __launch_bounds__(64) void snn_mask_build(const void* __restrict__ W,
                                                     const void* __restrict__ S,
                                                     unsigned char* __restrict__ MT) {
  __shared__ int flags_sh;
  const int tid = threadIdx.x;
  const int fl = sniff_flags(W, S, tid, &flags_sh);
  const bool s_bf = (fl & 2) != 0;
  const int tb = blockIdx.x;  // t-byte index: t = tb*8 + bit
  unsigned wrd[4] = {0u, 0u, 0u, 0u};
#pragma unroll
  for (int kk = 0; kk < 16; ++kk) {
    const int k = tid * 16 + kk;
    unsigned byte = 0;
    if (s_bf) {
      const unsigned short* Sb = (const unsigned short*)S;
      const uint4 u = *(const uint4*)&Sb[(size_t)k * SEQ_LEN + tb * 8];
      byte |= (((u.x & 0x7FFFu) != 0u) ? 1u : 0u) << 0;
      byte |= (((u.x & 0x7FFF0000u) != 0u) ? 1u : 0u) << 1;
      byte |= (((u.y & 0x7FFFu) != 0u) ? 1u : 0u) << 2;
      byte |= (((u.y & 0x7FFF0000u) != 0u) ? 1u : 0u) << 3;
      byte |= (((u.z & 0x7FFFu) != 0u) ? 1u : 0u) << 4;
      byte |= (((u.z & 0x7FFF0000u) != 0u) ? 1u : 0u) << 5;
      byte |= (((u.w & 0x7FFFu) != 0u) ? 1u : 0u) << 6;
      byte |= (((u.w & 0x7FFF0000u) != 0u) ? 1u : 0u) << 7;
    } else {
      const float* Sf = (const float*)S;
      const size_t base = (size_t)k * SEQ_LEN + tb * 8;
      const float4 f0 = *(const float4*)&Sf[base];
      const float4 f1 = *(const float4*)&Sf[base + 4];
      byte |= ((f0.x != 0.0f) ? 1u : 0u) << 0;
      byte |= ((f0.y != 0.0f) ? 1u : 0u) << 1;
      byte |= ((f0.z != 0.0f) ? 1u : 0u) << 2;
      byte |= ((f0.w != 0.0f) ? 1u : 0u) << 3;
      byte |= ((f1.x != 0.0f) ? 1u : 0u) << 4;
      byte |= ((f1.y != 0.0f) ? 1u : 0u) << 5;
      byte |= ((f1.z != 0.0f) ? 1u : 0u) << 6;
      byte |= ((f1.w != 0.0f) ? 1u : 0u) << 7;
    }
    wrd[kk >> 2] |= byte << ((kk & 3) * 8);
  }
  *(uint4*)&MT[(size_t)tb * N_PRE + tid * 16] =
      make_uint4(wrd[0], wrd[1], wrd[2], wrd[3]);
}

// ---------------- list build: MT -> per-t ascending spike list --------------
// One wave per t. Ordered compaction via ballot+prefix-popcount. Capacity is
// N_PRE entries per t -> overflow impossible. split = #entries with k < 512.
__global__ __launch_bounds__(64) void snn_list_build(const unsigned char* __restrict__ MT,
                                                     unsigned short* __restrict__ lists,
                                                     int* __restrict__ lens,
                                                     int* __restrict__ splits) {
  const int t = blockIdx.x;
  const int l = threadIdx.x;
  const unsigned char* Mrow = MT + (size_t)(t >> 3) * N_PRE;
  const int bit = t & 7;
  unsigned short* Lp = lists + (size_t)t * N_PRE;
  int base = 0;
  int split = 0;
#pragma unroll
  for (int c = 0; c < 16; ++c) {
    const int k = c * 64 + l;
    const int b = (Mrow[k] >> bit) & 1;
    const unsigned long long m = __ballot(b != 0);
    const int pre = __popcll(m & ((1ull << l) - 1ull));
    if (b) Lp[base + pre] = (unsigned short)k;
    base += __popcll(m);
    if (c == 7) split = base;
  }
  if (l == 0) {
    lens[t] = base;
    splits[t] = split;
  }
}

// ---------------- sparse GEMM: C[t][n] = sum over spiking k of WT[k][n] -----
// block = (t, n-half 1024); 256 thr x float4. lo-chain then hi-chain,
// ascending k (list order), combine rn(lo+hi). Bit-identical to the dense
// [512|512] chains (zero-adds skipped; see header comment).
__global__ __launch_bounds__(256) void snn_gemm_sp(const float* __restrict__ WT,
                                                   const unsigned short* __restrict__ lists,
                                                   const int* __restrict__ lens,
                                                   const int* __restrict__ splits,
                                                   float* __restrict__ C,
                                                   int t0, int ct) {
  const int tl = blockIdx.x;
  const int tg = t0 + tl;
  const int n = (int)blockIdx.y * 1024 + (int)threadIdx.x * 4;
  const unsigned short* __restrict__ L = lists + (size_t)tg * N_PRE;
  const int len = lens[tg];
  const int sp = splits[tg];
  float lo0 = 0.f, lo1 = 0.f, lo2 = 0.f, lo3 = 0.f;
  float hi0 = 0.f, hi1 = 0.f, hi2 = 0.f, hi3 = 0.f;
  int i = 0;
  for (; i < sp; ++i) {
    const int k = L[i];
    const float4 w = *(const float4*)&WT[((size_t)k << 11) + n];
    lo0 += w.x; lo1 += w.y; lo2 += w.z; lo3 += w.w;  // ascending chain, k<512
  }
  for (; i < len; ++i) {
    const int k = L[i];
    const float4 w = *(const float4*)&WT[((size_t)k << 11) + n];
    hi0 += w.x; hi1 += w.y; hi2 += w.z; hi3 += w.w;  // ascending chain, k>=512
  }
  *(float4*)&C[(size_t)tl * N_POST + n] =
      make_float4(lo0 + hi0, lo1 + hi1, lo2 + hi2, lo3 + hi3);  // rn(S1+S2)
}

// ---------------- Scan v4: 64 neurons/block, C[t][n] layout -----------------
// 32 blocks x 64 threads (1 wave). Lane l owns neuron n0+l: per-step c load
// is a coalesced 256B wave read of C[t][n0..64]. Full next-tile c prefetched
// into registers (64 regs, statically indexed) -> latency hidden under the
// 1024-cyc chain. s/v staged in LDS [t][n] (pad 65: (t+n)%32 banks, 2-way
// free) and flushed one tile behind, coalesced per n-row.
__global__ __launch_bounds__(64) void snn_scan_v4(const float* __restrict__ C,
                                                  float* __restrict__ spk,
                                                  float* __restrict__ vout,
                                                  float* __restrict__ v_carry,
                                                  int t0, int ct, int first) {
  __shared__ float sb[2][64][65];  // [buf][t][n]
  __shared__ float vb[2][64][65];
  const int l = threadIdx.x;
  const int n0 = blockIdx.x * 64;
  float v = 0.0f;
  if (!first) v = v_carry[n0 + l];
  const int ntiles = ct / 64;

  float ccur[64], cnxt[64];
#pragma unroll
  for (int j = 0; j < 64; ++j) ccur[j] = C[(size_t)j * N_POST + n0 + l];

  for (int tile = 0; tile < ntiles; ++tile) {
    __syncthreads();  // prev tile's LDS writes drained before flush reads
    const int buf = tile & 1;
    const bool havePrev = (tile > 0);
    const bool haveNext = (tile + 1 < ntiles);
#pragma unroll
    for (int g = 0; g < 4; ++g) {
      // prefetch next tile, group g (independent of chain)
      if (haveNext) {
#pragma unroll
        for (int j = 0; j < 16; ++j)
          cnxt[g * 16 + j] =
              C[(size_t)((tile + 1) * 64 + g * 16 + j) * N_POST + n0 + l];
      }
      // chain: 16 dependent LIF steps (DO NOT REORDER)
#pragma unroll
      for (int j = 0; j < 16; ++j) {
        const float c = ccur[g * 16 + j];
        const float leak = opaque(v * 0.9f);  // rn(v*0.9f)
        v = leak + c;                         // rn(+c)
        const bool fired = (v >= 1.0f);
        const float s = fired ? 1.0f : 0.0f;
        v = fired ? 0.0f : v;
        sb[buf][g * 16 + j][l] = s;
        vb[buf][g * 16 + j][l] = v;
      }
      // flush prev tile, rows g*16..+16 (reads [t=l][n=row]: 2-way banks)
      if (havePrev) {
        const int pb = buf ^ 1;
        const size_t gt = (size_t)t0 + (size_t)(tile - 1) * 64 + l;
#pragma unroll
        for (int r = 0; r < 16; ++r) {
          const int row = g * 16 + r;
          const size_t go = (size_t)(n0 + row) * SEQ_LEN + gt;
          spk[go] = sb[pb][l][row];
          vout[go] = vb[pb][l][row];
        }
      }
    }
#pragma unroll
    for (int j = 0; j < 64; ++j) ccur[j] = cnxt[j];
  }
  __syncthreads();
  {
    const int pb = (ntiles - 1) & 1;
    const size_t gt = (size_t)t0 + (size_t)(ntiles - 1) * 64 + l;
#pragma unroll
    for (int row = 0; row < 64; ++row) {
      const size_t go = (size_t)(n0 + row) * SEQ_LEN + gt;
      spk[go] = sb[pb][l][row];
      vout[go] = vb[pb][l][row];
    }
  }
  v_carry[n0 + l] = v;
}

// ---------------- fused fallback (ws too small), same [512|512] chain -------
__global__ __launch_bounds__(256) void snn_fused_blis(const void* __restrict__ W,
                                                      const void* __restrict__ S,
                                                      float* __restrict__ spk,
                                                      float* __restrict__ vout) {
  __shared__ float As[16][68];
  __shared__ float Bs[16][68];
  __shared__ float Ct[64][65];
  __shared__ float vsh[64];
  __shared__ int flags_sh;
  const int tid = threadIdx.x;
  const int fl = sniff_flags(W, S, tid, &flags_sh);
  const bool w_bf = (fl & 1) != 0;
  const bool s_bf = (fl & 2) != 0;

  const int tx = tid & 15;
  const int ty = tid >> 4;
  const int m0 = blockIdx.x * 64;
  if (tid < 64) vsh[tid] = 0.0f;

  for (int t0 = 0; t0 < SEQ_LEN; t0 += 64) {
    float acc0[4][4] = {{0.f}};
    float acc1[4][4] = {{0.f}};
    int k0 = 0;
#define FUSED_SEGMENT(ACC, KEND)                                                 \
    for (; k0 < (KEND); k0 += 16) {                                              \
      {                                                                          \
        const int r = tid >> 4, c = tid & 15;                                    \
        _Pragma("unroll") for (int j = 0; j < 4; ++j)                            \
            As[c][r + 16 * j] =                                                  \
                load_dyn(W, (size_t)(m0 + r + 16 * j) * N_PRE + k0 + c, w_bf);   \
      }                                                                          \
      {                                                                          \
        const int r = tid >> 6, c = tid & 63;                                    \
        _Pragma("unroll") for (int j = 0; j < 4; ++j)                            \
            Bs[r + 4 * j][c] =                                                   \
                load_dyn(S, (size_t)(k0 + r + 4 * j) * SEQ_LEN + t0 + c, s_bf);  \
      }                                                                          \
      __syncthreads();                                                           \
      _Pragma("unroll") for (int k = 0; k < 16; ++k) {                           \
        _Pragma("unroll") for (int i = 0; i < 4; ++i)                            \
            _Pragma("unroll") for (int j = 0; j < 4; ++j)                        \
                ACC[i][j] += As[k][ty * 4 + i] * Bs[k][tx * 4 + j];              \
      }                                                                          \
      __syncthreads();                                                           \
    }

    FUSED_SEGMENT(acc0, KSPLIT)
    FUSED_SEGMENT(acc1, N_PRE)
#undef FUSED_SEGMENT

#pragma unroll
    for (int i = 0; i < 4; ++i)
#pragma unroll
      for (int j = 0; j < 4; ++j) Ct[ty * 4 + i][tx * 4 + j] = acc0[i][j] + acc1[i][j];
    __syncthreads();
    if (tid < 64) {
      float v = vsh[tid];
#pragma unroll
      for (int k = 0; k < 64; ++k) {
        const float leak = opaque(v * 0.9f);
        v = leak + Ct[tid][k];
        const bool fired = (v >= 1.0f);
        const size_t g = (size_t)(m0 + tid) * SEQ_LEN + t0 + k;
        spk[g] = fired ? 1.0f : 0.0f;
        v = fired ? 0.0f : v;
        vout[g] = v;
      }
      vsh[tid] = v;
    }
    __syncthreads();
  }
}

extern "C" void kernel_launch(void* const* d_in, const int* in_sizes, int n_in,
                              void* d_out, int out_size, void* d_ws, size_t ws_size,
                              hipStream_t stream) {
  const void* stim = d_in[0];
  const void* weights = d_in[1];
  if (n_in >= 2 && in_sizes[0] == N_POST * N_PRE && in_sizes[1] == N_PRE * SEQ_LEN) {
    weights = d_in[0];
    stim = d_in[1];
  }

  float* spk = (float*)d_out;                    // output 0: spikes [N_POST, SEQ_LEN]
  float* vout = spk + (size_t)N_POST * SEQ_LEN;  // output 1: v      [N_POST, SEQ_LEN]

  // ---- workspace carve ----
  char* p = (char*)d_ws;
  float* WT = (float*)p;                 p += (size_t)N_PRE * N_POST * 4;      // 8 MB
  unsigned char* MT = (unsigned char*)p; p += (size_t)(SEQ_LEN / 8) * N_PRE;   // 512 KB
  unsigned short* lists = (unsigned short*)p; p += (size_t)SEQ_LEN * N_PRE * 2;// 8 MB
  int* lens = (int*)p;                   p += (size_t)SEQ_LEN * 4;             // 16 KB
  int* splits = (int*)p;                 p += (size_t)SEQ_LEN * 4;             // 16 KB
  float* v_carry = (float*)p;            p += (size_t)N_POST * 4;              // 8 KB
  float* C = (float*)p;
  const size_t used = (size_t)(p - (char*)d_ws);
  const size_t remain = (ws_size > used) ? (ws_size - used) : 0;

  int chunkT = (int)((remain / ((size_t)N_POST * sizeof(float))) / 64 * 64);
  if (chunkT > SEQ_LEN) chunkT = SEQ_LEN;
  if (chunkT >= 64) {  // round to power of two so chunkT divides SEQ_LEN
    int pw = 64;
    while (pw * 2 <= chunkT && pw < SEQ_LEN) pw *= 2;
    chunkT = pw;
  }

  if (chunkT >= 64) {
    snn_wt_build<<<dim3(N_PRE / 64, N_POST / 64), dim3(256), 0, stream>>>(weights, stim, WT);
    snn_mask_build<<<dim3(SEQ_LEN / 8), dim3(64), 0, stream>>>(weights, stim, MT);
    snn_list_build<<<dim3(SEQ_LEN), dim3(64), 0, stream>>>(MT, lists, lens, splits);
    for (int t0 = 0; t0 < SEQ_LEN; t0 += chunkT) {
      const int ct = (SEQ_LEN - t0 < chunkT) ? (SEQ_LEN - t0) : chunkT;  // mult of 64
      snn_gemm_sp<<<dim3(ct, 2), dim3(256), 0, stream>>>(WT, lists, lens, splits, C, t0, ct);
      snn_scan_v4<<<dim3(N_POST / 64), dim3(64), 0, stream>>>(C, spk, vout, v_carry,
                                                              t0, ct, t0 == 0);
    }
  } else {
    snn_fused_blis<<<dim3(N_POST / 64), dim3(256), 0, stream>>>(weights, stim, spk, vout);
  }
}

// Round 7
// 537.368 us; speedup vs baseline: 1.0501x; 1.0501x over previous
//
#include <hip/hip_runtime.h>

#define N_PRE 1024
#define N_POST 2048
#define SEQ_LEN 4096

// Reference-verified numerics (R11 PASS): per C element two fp32 segment
// chains k in [0,512) and [512,1024), ascending, single accumulator each,
// combined rn(S1+S2). stim in {0,1} -> products exact -> FMA == mul+add.
// Scan: v = rn(rn(v*0.9f) + c), fire >= 1.0f, reset 0. DO NOT REORDER.
//
// Sparse (v6, PASS absmax 0.015625): skipping adds of exact +/-0.0 is
// BIT-IDENTICAL (acc starts +0.0; RN never yields -0.0 from a sum, so
// rn(acc + ±0) == acc). Walk the ascending per-t spike list: lo-chain k<512,
// hi-chain k>=512, write rn(lo+hi).
//
// v7: scan_v4 (302us, 0.8% VALUBusy -- barrier-serialized single-wave-ish
// blocks) replaced by scan_v5: 32 blocks x 1 wave, barrier-free, LDS
// transpose staging, reg-prefetched c. gemm_sp list walk batched 8-wide.
#define KSPLIT 512

__device__ __forceinline__ float opaque(float x) {
  asm volatile("" : "+v"(x));
  return x;
}

__device__ __forceinline__ float load_dyn(const void* p, size_t idx, bool isbf) {
  if (isbf) {
    const unsigned short b = ((const unsigned short*)p)[idx];
    return __uint_as_float(((unsigned int)b) << 16);
  }
  return ((const float*)p)[idx];
}

// Input-dtype sniff (established: weights fp32, stim bf16; kept for safety).
__device__ __forceinline__ int sniff_flags(const void* W, const void* S, int tid,
                                           int* flags_sh) {
  if (tid < 64) {
    const unsigned short* uw = (const unsigned short*)W;
    const float f = fabsf(__uint_as_float(((unsigned int)uw[tid * 2]) << 16));
    const bool big = !(f < 64.f);
    const unsigned long long wb = __ballot(big);
    const unsigned short* us = (const unsigned short*)S;
    int hit = 0;
    for (int j = 0; j < 64; ++j) hit |= (us[tid * 128 + 2 * j] == 0x3F80u) ? 1 : 0;
    const unsigned long long sb = __ballot(hit != 0);
    if (tid == 0) *flags_sh = ((wb == 0ull) ? 1 : 0) | ((sb != 0ull) ? 2 : 0);
  }
  __syncthreads();
  return *flags_sh;
}

// ---------------- WT build: W[n][k] -> WT[k][n] (fp32), LDS transpose -------
__global__ __launch_bounds__(256) void snn_wt_build(const void* __restrict__ W,
                                                    const void* __restrict__ S,
                                                    float* __restrict__ WT) {
  __shared__ float tile[64][65];
  __shared__ int flags_sh;
  const int tid = threadIdx.x;
  const int fl = sniff_flags(W, S, tid, &flags_sh);
  const bool w_bf = (fl & 1) != 0;
  const int k0 = blockIdx.x * 64;
  const int nn0 = blockIdx.y * 64;
  {
    const int r = tid >> 2;
    const int cq = tid & 3;
    if (!w_bf) {
      const float* Wf = (const float*)W;
#pragma unroll
      for (int p = 0; p < 4; ++p) {
        const int c = cq * 16 + p * 4;
        const float4 va = *(const float4*)&Wf[(size_t)(nn0 + r) * N_PRE + k0 + c];
        tile[c + 0][r] = va.x; tile[c + 1][r] = va.y;
        tile[c + 2][r] = va.z; tile[c + 3][r] = va.w;
      }
    } else {
#pragma unroll
      for (int p = 0; p < 4; ++p)
#pragma unroll
        for (int j = 0; j < 4; ++j) {
          const int c = cq * 16 + p * 4 + j;
          tile[c][r] = load_dyn(W, (size_t)(nn0 + r) * N_PRE + k0 + c, true);
        }
    }
  }
  __syncthreads();
  {
    const int kr = tid >> 2;
    const int nq = tid & 3;
#pragma unroll
    for (int p = 0; p < 4; ++p) {
      const int c = nq * 16 + p * 4;
      float4 o;
      o.x = tile[kr][c + 0]; o.y = tile[kr][c + 1];
      o.z = tile[kr][c + 2]; o.w = tile[kr][c + 3];
      *(float4*)&WT[(size_t)(k0 + kr) * N_POST + nn0 + c] = o;
    }
  }
}

// ---------------- mask build: stim -> MT[t/8][k] bitmask bytes --------------
__global__ __launch_bounds__(64) void snn_mask_build(const void* __restrict__ W,
                                                     const void* __restrict__ S,
                                                     unsigned char* __restrict__ MT) {
  __shared__ int flags_sh;
  const int tid = threadIdx.x;
  const int fl = sniff_flags(W, S, tid, &flags_sh);
  const bool s_bf = (fl & 2) != 0;
  const int tb = blockIdx.x;  // t-byte index: t = tb*8 + bit
  unsigned wrd[4] = {0u, 0u, 0u, 0u};
#pragma unroll
  for (int kk = 0; kk < 16; ++kk) {
    const int k = tid * 16 + kk;
    unsigned byte = 0;
    if (s_bf) {
      const unsigned short* Sb = (const unsigned short*)S;
      const uint4 u = *(const uint4*)&Sb[(size_t)k * SEQ_LEN + tb * 8];
      byte |= (((u.x & 0x7FFFu) != 0u) ? 1u : 0u) << 0;
      byte |= (((u.x & 0x7FFF0000u) != 0u) ? 1u : 0u) << 1;
      byte |= (((u.y & 0x7FFFu) != 0u) ? 1u : 0u) << 2;
      byte |= (((u.y & 0x7FFF0000u) != 0u) ? 1u : 0u) << 3;
      byte |= (((u.z & 0x7FFFu) != 0u) ? 1u : 0u) << 4;
      byte |= (((u.z & 0x7FFF0000u) != 0u) ? 1u : 0u) << 5;
      byte |= (((u.w & 0x7FFFu) != 0u) ? 1u : 0u) << 6;
      byte |= (((u.w & 0x7FFF0000u) != 0u) ? 1u : 0u) << 7;
    } else {
      const float* Sf = (const float*)S;
      const size_t base = (size_t)k * SEQ_LEN + tb * 8;
      const float4 f0 = *(const float4*)&Sf[base];
      const float4 f1 = *(const float4*)&Sf[base + 4];
      byte |= ((f0.x != 0.0f) ? 1u : 0u) << 0;
      byte |= ((f0.y != 0.0f) ? 1u : 0u) << 1;
      byte |= ((f0.z != 0.0f) ? 1u : 0u) << 2;
      byte |= ((f0.w != 0.0f) ? 1u : 0u) << 3;
      byte |= ((f1.x != 0.0f) ? 1u : 0u) << 4;
      byte |= ((f1.y != 0.0f) ? 1u : 0u) << 5;
      byte |= ((f1.z != 0.0f) ? 1u : 0u) << 6;
      byte |= ((f1.w != 0.0f) ? 1u : 0u) << 7;
    }
    wrd[kk >> 2] |= byte << ((kk & 3) * 8);
  }
  *(uint4*)&MT[(size_t)tb * N_PRE + tid * 16] =
      make_uint4(wrd[0], wrd[1], wrd[2], wrd[3]);
}

// ---------------- list build: MT -> per-t ascending spike list --------------
__global__ __launch_bounds__(64) void snn_list_build(const unsigned char* __restrict__ MT,
                                                     unsigned short* __restrict__ lists,
                                                     int* __restrict__ lens,
                                                     int* __restrict__ splits) {
  const int t = blockIdx.x;
  const int l = threadIdx.x;
  const unsigned char* Mrow = MT + (size_t)(t >> 3) * N_PRE;
  const int bit = t & 7;
  unsigned short* Lp = lists + (size_t)t * N_PRE;
  int base = 0;
  int split = 0;
#pragma unroll
  for (int c = 0; c < 16; ++c) {
    const int k = c * 64 + l;
    const int b = (Mrow[k] >> bit) & 1;
    const unsigned long long m = __ballot(b != 0);
    const int pre = __popcll(m & ((1ull << l) - 1ull));
    if (b) Lp[base + pre] = (unsigned short)k;
    base += __popcll(m);
    if (c == 7) split = base;
  }
  if (l == 0) {
    lens[t] = base;
    splits[t] = split;
  }
}

// ---------------- sparse GEMM: C[t][n] = sum over spiking k of WT[k][n] -----
// block = (t, n-half 1024); 256 thr x float4. 8-wide batched list walk:
// one uint4 = 8 u16 entries -> 8 independent WT loads in flight -> adds in
// ascending list order (bit-identical chain).
__global__ __launch_bounds__(256) void snn_gemm_sp(const float* __restrict__ WT,
                                                   const unsigned short* __restrict__ lists,
                                                   const int* __restrict__ lens,
                                                   const int* __restrict__ splits,
                                                   float* __restrict__ C,
                                                   int t0, int ct) {
  const int tl = blockIdx.x;
  const int tg = t0 + tl;
  const int n = (int)blockIdx.y * 1024 + (int)threadIdx.x * 4;
  const unsigned short* __restrict__ L = lists + (size_t)tg * N_PRE;
  const int len = lens[tg];
  const int sp = splits[tg];
  float a0 = 0.f, a1 = 0.f, a2 = 0.f, a3 = 0.f;  // active chain accumulator
  float lo0, lo1, lo2, lo3;

#define SP_ADD(K)                                                      \
  {                                                                    \
    const float4 w = *(const float4*)&WT[((size_t)(K) << 11) + n];     \
    a0 += w.x; a1 += w.y; a2 += w.z; a3 += w.w;                        \
  }
#define SP_BATCH8(I)                                                   \
  {                                                                    \
    const uint4 u = *(const uint4*)&L[I];                              \
    const int k0 = u.x & 0xFFFF, k1 = u.x >> 16;                       \
    const int k2 = u.y & 0xFFFF, k3 = u.y >> 16;                       \
    const int k4 = u.z & 0xFFFF, k5 = u.z >> 16;                       \
    const int k6 = u.w & 0xFFFF, k7 = u.w >> 16;                       \
    const float4 w0 = *(const float4*)&WT[((size_t)k0 << 11) + n];     \
    const float4 w1 = *(const float4*)&WT[((size_t)k1 << 11) + n];     \
    const float4 w2 = *(const float4*)&WT[((size_t)k2 << 11) + n];     \
    const float4 w3 = *(const float4*)&WT[((size_t)k3 << 11) + n];     \
    const float4 w4 = *(const float4*)&WT[((size_t)k4 << 11) + n];     \
    const float4 w5 = *(const float4*)&WT[((size_t)k5 << 11) + n];     \
    const float4 w6 = *(const float4*)&WT[((size_t)k6 << 11) + n];     \
    const float4 w7 = *(const float4*)&WT[((size_t)k7 << 11) + n];     \
    a0 += w0.x; a1 += w0.y; a2 += w0.z; a3 += w0.w;                    \
    a0 += w1.x; a1 += w1.y; a2 += w1.z; a3 += w1.w;                    \
    a0 += w2.x; a1 += w2.y; a2 += w2.z; a3 += w2.w;                    \
    a0 += w3.x; a1 += w3.y; a2 += w3.z; a3 += w3.w;                    \
    a0 += w4.x; a1 += w4.y; a2 += w4.z; a3 += w4.w;                    \
    a0 += w5.x; a1 += w5.y; a2 += w5.z; a3 += w5.w;                    \
    a0 += w6.x; a1 += w6.y; a2 += w6.z; a3 += w6.w;                    \
    a0 += w7.x; a1 += w7.y; a2 += w7.z; a3 += w7.w;                    \
  }

  int i = 0;
  // ---- lo chain: k in [0, 512), list-ascending ----
  for (; i + 8 <= sp; i += 8) SP_BATCH8(i)
  for (; i < sp; ++i) SP_ADD(L[i])
  lo0 = a0; lo1 = a1; lo2 = a2; lo3 = a3;
  a0 = a1 = a2 = a3 = 0.f;
  // ---- hi chain: k in [512, 1024), list-ascending ----
  for (; i < len && (i & 7) != 0; ++i) SP_ADD(L[i])
  for (; i + 8 <= len; i += 8) SP_BATCH8(i)
  for (; i < len; ++i) SP_ADD(L[i])
#undef SP_BATCH8
#undef SP_ADD

  *(float4*)&C[(size_t)tl * N_POST + n] =
      make_float4(lo0 + a0, lo1 + a1, lo2 + a2, lo3 + a3);  // rn(S1+S2)
}

// ---------------- Scan v5: 32 blocks x 1 wave, barrier-free -----------------
// Lane l owns neuron n0+l. Per 64-t tile: prefetch next 16 c's (coalesced
// 256B wave loads, independent of chain) -> 16-step LIF chain writes s/v to
// LDS [t][65] (banks (t+lane)%32, 2/bank = free) -> flush 64 rows coalesced
// (lane=t, 256B stores). Single wave => LDS program-order safe, NO barriers.
__global__ __launch_bounds__(64) void snn_scan_v5(const float* __restrict__ C,
                                                  float* __restrict__ spk,
                                                  float* __restrict__ vout,
                                                  float* __restrict__ v_carry,
                                                  int t0, int ct, int first) {
  __shared__ float sb[64][65];
  __shared__ float vb[64][65];
  const int l = threadIdx.x;
  const int n0 = blockIdx.x * 64;
  const int n = n0 + l;
  float v = 0.0f;
  if (!first) v = v_carry[n];
  const int ntiles = ct / 64;

  float ccur[16], cnxt[16];
#pragma unroll
  for (int j = 0; j < 16; ++j) ccur[j] = C[(size_t)j * N_POST + n];

  for (int tile = 0; tile < ntiles; ++tile) {
    const int tb = tile * 64;
#pragma unroll
    for (int g = 0; g < 4; ++g) {
      const int ntg = tb + (g + 1) * 16;  // next group's global-in-chunk t
      if (ntg < ct) {
#pragma unroll
        for (int j = 0; j < 16; ++j) cnxt[j] = C[(size_t)(ntg + j) * N_POST + n];
      }
      // chain: 16 dependent LIF steps (DO NOT REORDER)
#pragma unroll
      for (int j = 0; j < 16; ++j) {
        const float c = ccur[j];
        const float leak = opaque(v * 0.9f);  // rn(v*0.9f)
        v = leak + c;                         // rn(+c)
        const bool fired = (v >= 1.0f);
        sb[g * 16 + j][l] = fired ? 1.0f : 0.0f;
        v = fired ? 0.0f : v;
        vb[g * 16 + j][l] = v;
      }
#pragma unroll
      for (int j = 0; j < 16; ++j) ccur[j] = cnxt[j];
    }
    // flush tile: lane = t, row = neuron; coalesced 256B stores
    const size_t gt = (size_t)t0 + tb + l;
#pragma unroll
    for (int r = 0; r < 64; ++r) {
      const size_t go = (size_t)(n0 + r) * SEQ_LEN + gt;
      spk[go] = sb[l][r];
      vout[go] = vb[l][r];
    }
  }
  v_carry[n] = v;
}

// ---------------- fused fallback (ws too small), same [512|512] chain -------
__global__ __launch_bounds__(256) void snn_fused_blis(const void* __restrict__ W,
                                                      const void* __restrict__ S,
                                                      float* __restrict__ spk,
                                                      float* __restrict__ vout) {
  __shared__ float As[16][68];
  __shared__ float Bs[16][68];
  __shared__ float Ct[64][65];
  __shared__ float vsh[64];
  __shared__ int flags_sh;
  const int tid = threadIdx.x;
  const int fl = sniff_flags(W, S, tid, &flags_sh);
  const bool w_bf = (fl & 1) != 0;
  const bool s_bf = (fl & 2) != 0;

  const int tx = tid & 15;
  const int ty = tid >> 4;
  const int m0 = blockIdx.x * 64;
  if (tid < 64) vsh[tid] = 0.0f;

  for (int t0 = 0; t0 < SEQ_LEN; t0 += 64) {
    float acc0[4][4] = {{0.f}};
    float acc1[4][4] = {{0.f}};
    int k0 = 0;
#define FUSED_SEGMENT(ACC, KEND)                                                 \
    for (; k0 < (KEND); k0 += 16) {                                              \
      {                                                                          \
        const int r = tid >> 4, c = tid & 15;                                    \
        _Pragma("unroll") for (int j = 0; j < 4; ++j)                            \
            As[c][r + 16 * j] =                                                  \
                load_dyn(W, (size_t)(m0 + r + 16 * j) * N_PRE + k0 + c, w_bf);   \
      }                                                                          \
      {                                                                          \
        const int r = tid >> 6, c = tid & 63;                                    \
        _Pragma("unroll") for (int j = 0; j < 4; ++j)                            \
            Bs[r + 4 * j][c] =                                                   \
                load_dyn(S, (size_t)(k0 + r + 4 * j) * SEQ_LEN + t0 + c, s_bf);  \
      }                                                                          \
      __syncthreads();                                                           \
      _Pragma("unroll") for (int k = 0; k < 16; ++k) {                           \
        _Pragma("unroll") for (int i = 0; i < 4; ++i)                            \
            _Pragma("unroll") for (int j = 0; j < 4; ++j)                        \
                ACC[i][j] += As[k][ty * 4 + i] * Bs[k][tx * 4 + j];              \
      }                                                                          \
      __syncthreads();                                                           \
    }

    FUSED_SEGMENT(acc0, KSPLIT)
    FUSED_SEGMENT(acc1, N_PRE)
#undef FUSED_SEGMENT

#pragma unroll
    for (int i = 0; i < 4; ++i)
#pragma unroll
      for (int j = 0; j < 4; ++j) Ct[ty * 4 + i][tx * 4 + j] = acc0[i][j] + acc1[i][j];
    __syncthreads();
    if (tid < 64) {
      float v = vsh[tid];
#pragma unroll
      for (int k = 0; k < 64; ++k) {
        const float leak = opaque(v * 0.9f);
        v = leak + Ct[tid][k];
        const bool fired = (v >= 1.0f);
        const size_t g = (size_t)(m0 + tid) * SEQ_LEN + t0 + k;
        spk[g] = fired ? 1.0f : 0.0f;
        v = fired ? 0.0f : v;
        vout[g] = v;
      }
      vsh[tid] = v;
    }
    __syncthreads();
  }
}

extern "C" void kernel_launch(void* const* d_in, const int* in_sizes, int n_in,
                              void* d_out, int out_size, void* d_ws, size_t ws_size,
                              hipStream_t stream) {
  const void* stim = d_in[0];
  const void* weights = d_in[1];
  if (n_in >= 2 && in_sizes[0] == N_POST * N_PRE && in_sizes[1] == N_PRE * SEQ_LEN) {
    weights = d_in[0];
    stim = d_in[1];
  }

  float* spk = (float*)d_out;                    // output 0: spikes [N_POST, SEQ_LEN]
  float* vout = spk + (size_t)N_POST * SEQ_LEN;  // output 1: v      [N_POST, SEQ_LEN]

  // ---- workspace carve ----
  char* p = (char*)d_ws;
  float* WT = (float*)p;                 p += (size_t)N_PRE * N_POST * 4;      // 8 MB
  unsigned char* MT = (unsigned char*)p; p += (size_t)(SEQ_LEN / 8) * N_PRE;   // 512 KB
  unsigned short* lists = (unsigned short*)p; p += (size_t)SEQ_LEN * N_PRE * 2;// 8 MB
  int* lens = (int*)p;                   p += (size_t)SEQ_LEN * 4;             // 16 KB
  int* splits = (int*)p;                 p += (size_t)SEQ_LEN * 4;             // 16 KB
  float* v_carry = (float*)p;            p += (size_t)N_POST * 4;              // 8 KB
  float* C = (float*)p;
  const size_t used = (size_t)(p - (char*)d_ws);
  const size_t remain = (ws_size > used) ? (ws_size - used) : 0;

  int chunkT = (int)((remain / ((size_t)N_POST * sizeof(float))) / 64 * 64);
  if (chunkT > SEQ_LEN) chunkT = SEQ_LEN;
  if (chunkT >= 64) {  // round to power of two so chunkT divides SEQ_LEN
    int pw = 64;
    while (pw * 2 <= chunkT && pw < SEQ_LEN) pw *= 2;
    chunkT = pw;
  }

  if (chunkT >= 64) {
    snn_wt_build<<<dim3(N_PRE / 64, N_POST / 64), dim3(256), 0, stream>>>(weights, stim, WT);
    snn_mask_build<<<dim3(SEQ_LEN / 8), dim3(64), 0, stream>>>(weights, stim, MT);
    snn_list_build<<<dim3(SEQ_LEN), dim3(64), 0, stream>>>(MT, lists, lens, splits);
    for (int t0 = 0; t0 < SEQ_LEN; t0 += chunkT) {
      const int ct = (SEQ_LEN - t0 < chunkT) ? (SEQ_LEN - t0) : chunkT;  // mult of 64
      snn_gemm_sp<<<dim3(ct, 2), dim3(256), 0, stream>>>(WT, lists, lens, splits, C, t0, ct);
      snn_scan_v5<<<dim3(N_POST / 64), dim3(64), 0, stream>>>(C, spk, vout, v_carry,
                                                              t0, ct, t0 == 0);
    }
  } else {
    snn_fused_blis<<<dim3(N_POST / 64), dim3(256), 0, stream>>>(weights, stim, spk, vout);
  }
}

// Round 8
// 407.463 us; speedup vs baseline: 1.3849x; 1.3188x over previous
//
#include <hip/hip_runtime.h>

#define N_PRE 1024
#define N_POST 2048
#define SEQ_LEN 4096

// Reference-verified numerics (R11 PASS): per C element two fp32 segment
// chains k in [0,512) and [512,1024), ascending, single accumulator each,
// combined rn(S1+S2). stim in {0,1} -> products exact -> FMA == mul+add.
// Scan: v = rn(rn(v*0.9f) + c), fire >= 1.0f, reset 0. DO NOT REORDER.
//
// Sparse (v6, PASS absmax 0.015625): skipping adds of exact +/-0.0 is
// BIT-IDENTICAL (acc starts +0.0; RN never yields -0.0 from a sum, so
// rn(acc + ±0) == acc). Walk the ascending per-t spike list: lo-chain k<512,
// hi-chain k>=512, write rn(lo+hi).
//
// v8: scan split into checkpoint + replay. The 2048-neuron chain is only 32
// waves (chip 97% idle -- v5/v7 measured 307us at 0.8% VALUBusy). Phase 1
// (snn_scan_chk, 32 waves) runs the chain, stores v only at 64-t tile
// boundaries (512 KB). Phase 2 (snn_scan_emit, 2048 single-wave blocks =
// full chip) replays each 64-t tile from its checkpoint with IDENTICAL ops
// in IDENTICAL order (bitwise-equal v/s) and emits the 64 MB of outputs
// with float4 stores. Chain work x2, but chain is ~0.03% of chip FLOPs.
#define KSPLIT 512

__device__ __forceinline__ float opaque(float x) {
  asm volatile("" : "+v"(x));
  return x;
}

__device__ __forceinline__ float load_dyn(const void* p, size_t idx, bool isbf) {
  if (isbf) {
    const unsigned short b = ((const unsigned short*)p)[idx];
    return __uint_as_float(((unsigned int)b) << 16);
  }
  return ((const float*)p)[idx];
}

// Input-dtype sniff (established: weights fp32, stim bf16; kept for safety).
__device__ __forceinline__ int sniff_flags(const void* W, const void* S, int tid,
                                           int* flags_sh) {
  if (tid < 64) {
    const unsigned short* uw = (const unsigned short*)W;
    const float f = fabsf(__uint_as_float(((unsigned int)uw[tid * 2]) << 16));
    const bool big = !(f < 64.f);
    const unsigned long long wb = __ballot(big);
    const unsigned short* us = (const unsigned short*)S;
    int hit = 0;
    for (int j = 0; j < 64; ++j) hit |= (us[tid * 128 + 2 * j] == 0x3F80u) ? 1 : 0;
    const unsigned long long sb = __ballot(hit != 0);
    if (tid == 0) *flags_sh = ((wb == 0ull) ? 1 : 0) | ((sb != 0ull) ? 2 : 0);
  }
  __syncthreads();
  return *flags_sh;
}

// ---------------- WT build: W[n][k] -> WT[k][n] (fp32), LDS transpose -------
__global__ __launch_bounds__(256) void snn_wt_build(const void* __restrict__ W,
                                                    const void* __restrict__ S,
                                                    float* __restrict__ WT) {
  __shared__ float tile[64][65];
  __shared__ int flags_sh;
  const int tid = threadIdx.x;
  const int fl = sniff_flags(W, S, tid, &flags_sh);
  const bool w_bf = (fl & 1) != 0;
  const int k0 = blockIdx.x * 64;
  const int nn0 = blockIdx.y * 64;
  {
    const int r = tid >> 2;
    const int cq = tid & 3;
    if (!w_bf) {
      const float* Wf = (const float*)W;
#pragma unroll
      for (int p = 0; p < 4; ++p) {
        const int c = cq * 16 + p * 4;
        const float4 va = *(const float4*)&Wf[(size_t)(nn0 + r) * N_PRE + k0 + c];
        tile[c + 0][r] = va.x; tile[c + 1][r] = va.y;
        tile[c + 2][r] = va.z; tile[c + 3][r] = va.w;
      }
    } else {
#pragma unroll
      for (int p = 0; p < 4; ++p)
#pragma unroll
        for (int j = 0; j < 4; ++j) {
          const int c = cq * 16 + p * 4 + j;
          tile[c][r] = load_dyn(W, (size_t)(nn0 + r) * N_PRE + k0 + c, true);
        }
    }
  }
  __syncthreads();
  {
    const int kr = tid >> 2;
    const int nq = tid & 3;
#pragma unroll
    for (int p = 0; p < 4; ++p) {
      const int c = nq * 16 + p * 4;
      float4 o;
      o.x = tile[kr][c + 0]; o.y = tile[kr][c + 1];
      o.z = tile[kr][c + 2]; o.w = tile[kr][c + 3];
      *(float4*)&WT[(size_t)(k0 + kr) * N_POST + nn0 + c] = o;
    }
  }
}

// ---------------- mask build: stim -> MT[t/8][k] bitmask bytes --------------
__global__ __launch_bounds__(64) void snn_mask_build(const void* __restrict__ W,
                                                     const void* __restrict__ S,
                                                     unsigned char* __restrict__ MT) {
  __shared__ int flags_sh;
  const int tid = threadIdx.x;
  const int fl = sniff_flags(W, S, tid, &flags_sh);
  const bool s_bf = (fl & 2) != 0;
  const int tb = blockIdx.x;  // t-byte index: t = tb*8 + bit
  unsigned wrd[4] = {0u, 0u, 0u, 0u};
#pragma unroll
  for (int kk = 0; kk < 16; ++kk) {
    const int k = tid * 16 + kk;
    unsigned byte = 0;
    if (s_bf) {
      const unsigned short* Sb = (const unsigned short*)S;
      const uint4 u = *(const uint4*)&Sb[(size_t)k * SEQ_LEN + tb * 8];
      byte |= (((u.x & 0x7FFFu) != 0u) ? 1u : 0u) << 0;
      byte |= (((u.x & 0x7FFF0000u) != 0u) ? 1u : 0u) << 1;
      byte |= (((u.y & 0x7FFFu) != 0u) ? 1u : 0u) << 2;
      byte |= (((u.y & 0x7FFF0000u) != 0u) ? 1u : 0u) << 3;
      byte |= (((u.z & 0x7FFFu) != 0u) ? 1u : 0u) << 4;
      byte |= (((u.z & 0x7FFF0000u) != 0u) ? 1u : 0u) << 5;
      byte |= (((u.w & 0x7FFFu) != 0u) ? 1u : 0u) << 6;
      byte |= (((u.w & 0x7FFF0000u) != 0u) ? 1u : 0u) << 7;
    } else {
      const float* Sf = (const float*)S;
      const size_t base = (size_t)k * SEQ_LEN + tb * 8;
      const float4 f0 = *(const float4*)&Sf[base];
      const float4 f1 = *(const float4*)&Sf[base + 4];
      byte |= ((f0.x != 0.0f) ? 1u : 0u) << 0;
      byte |= ((f0.y != 0.0f) ? 1u : 0u) << 1;
      byte |= ((f0.z != 0.0f) ? 1u : 0u) << 2;
      byte |= ((f0.w != 0.0f) ? 1u : 0u) << 3;
      byte |= ((f1.x != 0.0f) ? 1u : 0u) << 4;
      byte |= ((f1.y != 0.0f) ? 1u : 0u) << 5;
      byte |= ((f1.z != 0.0f) ? 1u : 0u) << 6;
      byte |= ((f1.w != 0.0f) ? 1u : 0u) << 7;
    }
    wrd[kk >> 2] |= byte << ((kk & 3) * 8);
  }
  *(uint4*)&MT[(size_t)tb * N_PRE + tid * 16] =
      make_uint4(wrd[0], wrd[1], wrd[2], wrd[3]);
}

// ---------------- list build: MT -> per-t ascending spike list --------------
__global__ __launch_bounds__(64) void snn_list_build(const unsigned char* __restrict__ MT,
                                                     unsigned short* __restrict__ lists,
                                                     int* __restrict__ lens,
                                                     int* __restrict__ splits) {
  const int t = blockIdx.x;
  const int l = threadIdx.x;
  const unsigned char* Mrow = MT + (size_t)(t >> 3) * N_PRE;
  const int bit = t & 7;
  unsigned short* Lp = lists + (size_t)t * N_PRE;
  int base = 0;
  int split = 0;
#pragma unroll
  for (int c = 0; c < 16; ++c) {
    const int k = c * 64 + l;
    const int b = (Mrow[k] >> bit) & 1;
    const unsigned long long m = __ballot(b != 0);
    const int pre = __popcll(m & ((1ull << l) - 1ull));
    if (b) Lp[base + pre] = (unsigned short)k;
    base += __popcll(m);
    if (c == 7) split = base;
  }
  if (l == 0) {
    lens[t] = base;
    splits[t] = split;
  }
}

// ---------------- sparse GEMM: C[t][n] = sum over spiking k of WT[k][n] -----
// block = (t, n-half 1024); 256 thr x float4. 8-wide batched list walk:
// one uint4 = 8 u16 entries -> 8 independent WT loads in flight -> adds in
// ascending list order (bit-identical chain).
__global__ __launch_bounds__(256) void snn_gemm_sp(const float* __restrict__ WT,
                                                   const unsigned short* __restrict__ lists,
                                                   const int* __restrict__ lens,
                                                   const int* __restrict__ splits,
                                                   float* __restrict__ C,
                                                   int t0, int ct) {
  const int tl = blockIdx.x;
  const int tg = t0 + tl;
  const int n = (int)blockIdx.y * 1024 + (int)threadIdx.x * 4;
  const unsigned short* __restrict__ L = lists + (size_t)tg * N_PRE;
  const int len = lens[tg];
  const int sp = splits[tg];
  float a0 = 0.f, a1 = 0.f, a2 = 0.f, a3 = 0.f;  // active chain accumulator
  float lo0, lo1, lo2, lo3;

#define SP_ADD(K)                                                      \
  {                                                                    \
    const float4 w = *(const float4*)&WT[((size_t)(K) << 11) + n];     \
    a0 += w.x; a1 += w.y; a2 += w.z; a3 += w.w;                        \
  }
#define SP_BATCH8(I)                                                   \
  {                                                                    \
    const uint4 u = *(const uint4*)&L[I];                              \
    const int k0 = u.x & 0xFFFF, k1 = u.x >> 16;                       \
    const int k2 = u.y & 0xFFFF, k3 = u.y >> 16;                       \
    const int k4 = u.z & 0xFFFF, k5 = u.z >> 16;                       \
    const int k6 = u.w & 0xFFFF, k7 = u.w >> 16;                       \
    const float4 w0 = *(const float4*)&WT[((size_t)k0 << 11) + n];     \
    const float4 w1 = *(const float4*)&WT[((size_t)k1 << 11) + n];     \
    const float4 w2 = *(const float4*)&WT[((size_t)k2 << 11) + n];     \
    const float4 w3 = *(const float4*)&WT[((size_t)k3 << 11) + n];     \
    const float4 w4 = *(const float4*)&WT[((size_t)k4 << 11) + n];     \
    const float4 w5 = *(const float4*)&WT[((size_t)k5 << 11) + n];     \
    const float4 w6 = *(const float4*)&WT[((size_t)k6 << 11) + n];     \
    const float4 w7 = *(const float4*)&WT[((size_t)k7 << 11) + n];     \
    a0 += w0.x; a1 += w0.y; a2 += w0.z; a3 += w0.w;                    \
    a0 += w1.x; a1 += w1.y; a2 += w1.z; a3 += w1.w;                    \
    a0 += w2.x; a1 += w2.y; a2 += w2.z; a3 += w2.w;                    \
    a0 += w3.x; a1 += w3.y; a2 += w3.z; a3 += w3.w;                    \
    a0 += w4.x; a1 += w4.y; a2 += w4.z; a3 += w4.w;                    \
    a0 += w5.x; a1 += w5.y; a2 += w5.z; a3 += w5.w;                    \
    a0 += w6.x; a1 += w6.y; a2 += w6.z; a3 += w6.w;                    \
    a0 += w7.x; a1 += w7.y; a2 += w7.z; a3 += w7.w;                    \
  }

  int i = 0;
  // ---- lo chain: k in [0, 512), list-ascending ----
  for (; i + 8 <= sp; i += 8) SP_BATCH8(i)
  for (; i < sp; ++i) SP_ADD(L[i])
  lo0 = a0; lo1 = a1; lo2 = a2; lo3 = a3;
  a0 = a1 = a2 = a3 = 0.f;
  // ---- hi chain: k in [512, 1024), list-ascending ----
  for (; i < len && (i & 7) != 0; ++i) SP_ADD(L[i])
  for (; i + 8 <= len; i += 8) SP_BATCH8(i)
  for (; i < len; ++i) SP_ADD(L[i])
#undef SP_BATCH8
#undef SP_ADD

  *(float4*)&C[(size_t)tl * N_POST + n] =
      make_float4(lo0 + a0, lo1 + a1, lo2 + a2, lo3 + a3);  // rn(S1+S2)
}

// ---------------- Scan phase 1: checkpoint chain (32 waves) -----------------
// Lane l = neuron n0+l. Runs the full chain over the chunk; stores v ONLY at
// each 64-t tile entry (vchk[tile][n], 512 KB total) + final v_carry.
// Reg-prefetched C column loads; no LDS, no barriers, no output stores.
__global__ __launch_bounds__(64) void snn_scan_chk(const float* __restrict__ C,
                                                   float* __restrict__ vchk,
                                                   float* __restrict__ v_carry,
                                                   int ct, int first) {
  const int l = threadIdx.x;
  const int n = blockIdx.x * 64 + l;
  float v = 0.0f;
  if (!first) v = v_carry[n];
  const int ntiles = ct / 64;

  float ccur[16], cnxt[16];
#pragma unroll
  for (int j = 0; j < 16; ++j) ccur[j] = C[(size_t)j * N_POST + n];

  for (int tile = 0; tile < ntiles; ++tile) {
    vchk[(size_t)tile * N_POST + n] = v;  // carry-in for this tile
    const int tb = tile * 64;
#pragma unroll
    for (int g = 0; g < 4; ++g) {
      const int ntg = tb + (g + 1) * 16;
      if (ntg < ct) {
#pragma unroll
        for (int j = 0; j < 16; ++j) cnxt[j] = C[(size_t)(ntg + j) * N_POST + n];
      }
      // chain: 16 dependent LIF steps (DO NOT REORDER; identical to emit)
#pragma unroll
      for (int j = 0; j < 16; ++j) {
        const float c = ccur[j];
        const float leak = opaque(v * 0.9f);  // rn(v*0.9f)
        v = leak + c;                         // rn(+c)
        const bool fired = (v >= 1.0f);
        v = fired ? 0.0f : v;
      }
#pragma unroll
      for (int j = 0; j < 16; ++j) ccur[j] = cnxt[j];
    }
  }
  v_carry[n] = v;
}

// ---------------- Scan phase 2: replay + emit (full chip) -------------------
// Block (n-group, tile): 1 wave, replays the 64-step chain from vchk with
// IDENTICAL ops/order (bitwise-equal s,v), stages in LDS [t][65]
// (chain writes bank (t+l)%32 conflict-free; flush reads 2-way = free),
// emits float4-wide on t. 2048 blocks -> full chip for the 64 MB of stores.
__global__ __launch_bounds__(64) void snn_scan_emit(const float* __restrict__ C,
                                                    const float* __restrict__ vchk,
                                                    float* __restrict__ spk,
                                                    float* __restrict__ vout,
                                                    int t0, int ct) {
  __shared__ float sb[64][65];
  __shared__ float vb[64][65];
  const int l = threadIdx.x;
  const int n0 = blockIdx.x * 64;
  const int tile = blockIdx.y;
  const int n = n0 + l;
  const int tb = tile * 64;

  float v = vchk[(size_t)tile * N_POST + n];

  float ccur[16], cnxt[16];
#pragma unroll
  for (int j = 0; j < 16; ++j) ccur[j] = C[(size_t)(tb + j) * N_POST + n];

#pragma unroll
  for (int g = 0; g < 4; ++g) {
    if (g < 3) {
#pragma unroll
      for (int j = 0; j < 16; ++j)
        cnxt[j] = C[(size_t)(tb + (g + 1) * 16 + j) * N_POST + n];
    }
    // chain: 16 dependent LIF steps (DO NOT REORDER; identical to chk)
#pragma unroll
    for (int j = 0; j < 16; ++j) {
      const float c = ccur[j];
      const float leak = opaque(v * 0.9f);  // rn(v*0.9f)
      v = leak + c;                         // rn(+c)
      const bool fired = (v >= 1.0f);
      sb[g * 16 + j][l] = fired ? 1.0f : 0.0f;
      v = fired ? 0.0f : v;
      vb[g * 16 + j][l] = v;
    }
#pragma unroll
    for (int j = 0; j < 16; ++j) ccur[j] = cnxt[j];
  }

  // flush: 16 iters x (4 rows x 16 lanes x float4-on-t); single wave =>
  // program order makes LDS writes visible, no barrier needed.
  const int t4 = (l & 15) * 4;
  const int rq = l >> 4;
  const size_t gtb = (size_t)t0 + tb;
#pragma unroll
  for (int it = 0; it < 16; ++it) {
    const int r = it * 4 + rq;  // neuron row within group
    float4 so, vo;
    so.x = sb[t4 + 0][r]; so.y = sb[t4 + 1][r];
    so.z = sb[t4 + 2][r]; so.w = sb[t4 + 3][r];
    vo.x = vb[t4 + 0][r]; vo.y = vb[t4 + 1][r];
    vo.z = vb[t4 + 2][r]; vo.w = vb[t4 + 3][r];
    const size_t go = (size_t)(n0 + r) * SEQ_LEN + gtb + t4;
    *(float4*)&spk[go] = so;
    *(float4*)&vout[go] = vo;
  }
}

// ---------------- fused fallback (ws too small), same [512|512] chain -------
__global__ __launch_bounds__(256) void snn_fused_blis(const void* __restrict__ W,
                                                      const void* __restrict__ S,
                                                      float* __restrict__ spk,
                                                      float* __restrict__ vout) {
  __shared__ float As[16][68];
  __shared__ float Bs[16][68];
  __shared__ float Ct[64][65];
  __shared__ float vsh[64];
  __shared__ int flags_sh;
  const int tid = threadIdx.x;
  const int fl = sniff_flags(W, S, tid, &flags_sh);
  const bool w_bf = (fl & 1) != 0;
  const bool s_bf = (fl & 2) != 0;

  const int tx = tid & 15;
  const int ty = tid >> 4;
  const int m0 = blockIdx.x * 64;
  if (tid < 64) vsh[tid] = 0.0f;

  for (int t0 = 0; t0 < SEQ_LEN; t0 += 64) {
    float acc0[4][4] = {{0.f}};
    float acc1[4][4] = {{0.f}};
    int k0 = 0;
#define FUSED_SEGMENT(ACC, KEND)                                                 \
    for (; k0 < (KEND); k0 += 16) {                                              \
      {                                                                          \
        const int r = tid >> 4, c = tid & 15;                                    \
        _Pragma("unroll") for (int j = 0; j < 4; ++j)                            \
            As[c][r + 16 * j] =                                                  \
                load_dyn(W, (size_t)(m0 + r + 16 * j) * N_PRE + k0 + c, w_bf);   \
      }                                                                          \
      {                                                                          \
        const int r = tid >> 6, c = tid & 63;                                    \
        _Pragma("unroll") for (int j = 0; j < 4; ++j)                            \
            Bs[r + 4 * j][c] =                                                   \
                load_dyn(S, (size_t)(k0 + r + 4 * j) * SEQ_LEN + t0 + c, s_bf);  \
      }                                                                          \
      __syncthreads();                                                           \
      _Pragma("unroll") for (int k = 0; k < 16; ++k) {                           \
        _Pragma("unroll") for (int i = 0; i < 4; ++i)                            \
            _Pragma("unroll") for (int j = 0; j < 4; ++j)                        \
                ACC[i][j] += As[k][ty * 4 + i] * Bs[k][tx * 4 + j];              \
      }                                                                          \
      __syncthreads();                                                           \
    }

    FUSED_SEGMENT(acc0, KSPLIT)
    FUSED_SEGMENT(acc1, N_PRE)
#undef FUSED_SEGMENT

#pragma unroll
    for (int i = 0; i < 4; ++i)
#pragma unroll
      for (int j = 0; j < 4; ++j) Ct[ty * 4 + i][tx * 4 + j] = acc0[i][j] + acc1[i][j];
    __syncthreads();
    if (tid < 64) {
      float v = vsh[tid];
#pragma unroll
      for (int k = 0; k < 64; ++k) {
        const float leak = opaque(v * 0.9f);
        v = leak + Ct[tid][k];
        const bool fired = (v >= 1.0f);
        const size_t g = (size_t)(m0 + tid) * SEQ_LEN + t0 + k;
        spk[g] = fired ? 1.0f : 0.0f;
        v = fired ? 0.0f : v;
        vout[g] = v;
      }
      vsh[tid] = v;
    }
    __syncthreads();
  }
}

extern "C" void kernel_launch(void* const* d_in, const int* in_sizes, int n_in,
                              void* d_out, int out_size, void* d_ws, size_t ws_size,
                              hipStream_t stream) {
  const void* stim = d_in[0];
  const void* weights = d_in[1];
  if (n_in >= 2 && in_sizes[0] == N_POST * N_PRE && in_sizes[1] == N_PRE * SEQ_LEN) {
    weights = d_in[0];
    stim = d_in[1];
  }

  float* spk = (float*)d_out;                    // output 0: spikes [N_POST, SEQ_LEN]
  float* vout = spk + (size_t)N_POST * SEQ_LEN;  // output 1: v      [N_POST, SEQ_LEN]

  // ---- workspace carve ----
  char* p = (char*)d_ws;
  float* WT = (float*)p;                 p += (size_t)N_PRE * N_POST * 4;      // 8 MB
  unsigned char* MT = (unsigned char*)p; p += (size_t)(SEQ_LEN / 8) * N_PRE;   // 512 KB
  unsigned short* lists = (unsigned short*)p; p += (size_t)SEQ_LEN * N_PRE * 2;// 8 MB
  int* lens = (int*)p;                   p += (size_t)SEQ_LEN * 4;             // 16 KB
  int* splits = (int*)p;                 p += (size_t)SEQ_LEN * 4;             // 16 KB
  float* v_carry = (float*)p;            p += (size_t)N_POST * 4;              // 8 KB
  float* vchk = (float*)p;               p += (size_t)(SEQ_LEN / 64) * N_POST * 4;  // 512 KB
  float* C = (float*)p;
  const size_t used = (size_t)(p - (char*)d_ws);
  const size_t remain = (ws_size > used) ? (ws_size - used) : 0;

  int chunkT = (int)((remain / ((size_t)N_POST * sizeof(float))) / 64 * 64);
  if (chunkT > SEQ_LEN) chunkT = SEQ_LEN;
  if (chunkT >= 64) {  // round to power of two so chunkT divides SEQ_LEN
    int pw = 64;
    while (pw * 2 <= chunkT && pw < SEQ_LEN) pw *= 2;
    chunkT = pw;
  }

  if (chunkT >= 64) {
    snn_wt_build<<<dim3(N_PRE / 64, N_POST / 64), dim3(256), 0, stream>>>(weights, stim, WT);
    snn_mask_build<<<dim3(SEQ_LEN / 8), dim3(64), 0, stream>>>(weights, stim, MT);
    snn_list_build<<<dim3(SEQ_LEN), dim3(64), 0, stream>>>(MT, lists, lens, splits);
    for (int t0 = 0; t0 < SEQ_LEN; t0 += chunkT) {
      const int ct = (SEQ_LEN - t0 < chunkT) ? (SEQ_LEN - t0) : chunkT;  // mult of 64
      snn_gemm_sp<<<dim3(ct, 2), dim3(256), 0, stream>>>(WT, lists, lens, splits, C, t0, ct);
      snn_scan_chk<<<dim3(N_POST / 64), dim3(64), 0, stream>>>(C, vchk, v_carry,
                                                               ct, t0 == 0);
      snn_scan_emit<<<dim3(N_POST / 64, ct / 64), dim3(64), 0, stream>>>(C, vchk, spk,
                                                                         vout, t0, ct);
    }
  } else {
    snn_fused_blis<<<dim3(N_POST / 64), dim3(256), 0, stream>>>(weights, stim, spk, vout);
  }
}

// Round 9
// 362.910 us; speedup vs baseline: 1.5550x; 1.1228x over previous
//
#include <hip/hip_runtime.h>

#define N_PRE 1024
#define N_POST 2048
#define SEQ_LEN 4096

// Reference-verified numerics (R11 PASS): per C element two fp32 segment
// chains k in [0,512) and [512,1024), ascending, single accumulator each,
// combined rn(S1+S2). stim in {0,1} -> products exact -> FMA == mul+add.
// Scan: v = rn(rn(v*0.9f) + c), fire >= 1.0f, reset 0. DO NOT REORDER.
//
// Sparse (v6, PASS absmax 0.015625): skipping adds of exact +/-0.0 is
// BIT-IDENTICAL (acc starts +0.0; RN never yields -0.0 from a sum, so
// rn(acc + ±0) == acc). Walk the ascending per-t spike list: lo-chain k<512,
// hi-chain k>=512, write rn(lo+hi).
//
// v8 (PASS, 407us): checkpoint chain (32 waves, v at 64-t boundaries) +
// full-chip replay/emit. v9: chk was 158us = 92 cyc/step -- prefetch depth
// (16) << C-load latency (~900 cyc from cross-XCD L2/HBM at 1 wave/CU).
// Now prefetches the ENTIRE next 64-t tile (64 loads in flight, 256-1024
// cyc cover). Chain ops identical -> bitwise-equal results.
#define KSPLIT 512

__device__ __forceinline__ float opaque(float x) {
  asm volatile("" : "+v"(x));
  return x;
}

__device__ __forceinline__ float load_dyn(const void* p, size_t idx, bool isbf) {
  if (isbf) {
    const unsigned short b = ((const unsigned short*)p)[idx];
    return __uint_as_float(((unsigned int)b) << 16);
  }
  return ((const float*)p)[idx];
}

// Input-dtype sniff (established: weights fp32, stim bf16; kept for safety).
__device__ __forceinline__ int sniff_flags(const void* W, const void* S, int tid,
                                           int* flags_sh) {
  if (tid < 64) {
    const unsigned short* uw = (const unsigned short*)W;
    const float f = fabsf(__uint_as_float(((unsigned int)uw[tid * 2]) << 16));
    const bool big = !(f < 64.f);
    const unsigned long long wb = __ballot(big);
    const unsigned short* us = (const unsigned short*)S;
    int hit = 0;
    for (int j = 0; j < 64; ++j) hit |= (us[tid * 128 + 2 * j] == 0x3F80u) ? 1 : 0;
    const unsigned long long sb = __ballot(hit != 0);
    if (tid == 0) *flags_sh = ((wb == 0ull) ? 1 : 0) | ((sb != 0ull) ? 2 : 0);
  }
  __syncthreads();
  return *flags_sh;
}

// ---------------- WT build: W[n][k] -> WT[k][n] (fp32), LDS transpose -------
__global__ __launch_bounds__(256) void snn_wt_build(const void* __restrict__ W,
                                                    const void* __restrict__ S,
                                                    float* __restrict__ WT) {
  __shared__ float tile[64][65];
  __shared__ int flags_sh;
  const int tid = threadIdx.x;
  const int fl = sniff_flags(W, S, tid, &flags_sh);
  const bool w_bf = (fl & 1) != 0;
  const int k0 = blockIdx.x * 64;
  const int nn0 = blockIdx.y * 64;
  {
    const int r = tid >> 2;
    const int cq = tid & 3;
    if (!w_bf) {
      const float* Wf = (const float*)W;
#pragma unroll
      for (int p = 0; p < 4; ++p) {
        const int c = cq * 16 + p * 4;
        const float4 va = *(const float4*)&Wf[(size_t)(nn0 + r) * N_PRE + k0 + c];
        tile[c + 0][r] = va.x; tile[c + 1][r] = va.y;
        tile[c + 2][r] = va.z; tile[c + 3][r] = va.w;
      }
    } else {
#pragma unroll
      for (int p = 0; p < 4; ++p)
#pragma unroll
        for (int j = 0; j < 4; ++j) {
          const int c = cq * 16 + p * 4 + j;
          tile[c][r] = load_dyn(W, (size_t)(nn0 + r) * N_PRE + k0 + c, true);
        }
    }
  }
  __syncthreads();
  {
    const int kr = tid >> 2;
    const int nq = tid & 3;
#pragma unroll
    for (int p = 0; p < 4; ++p) {
      const int c = nq * 16 + p * 4;
      float4 o;
      o.x = tile[kr][c + 0]; o.y = tile[kr][c + 1];
      o.z = tile[kr][c + 2]; o.w = tile[kr][c + 3];
      *(float4*)&WT[(size_t)(k0 + kr) * N_POST + nn0 + c] = o;
    }
  }
}

// ---------------- mask build: stim -> MT[t/8][k] bitmask bytes --------------
__global__ __launch_bounds__(64) void snn_mask_build(const void* __restrict__ W,
                                                     const void* __restrict__ S,
                                                     unsigned char* __restrict__ MT) {
  __shared__ int flags_sh;
  const int tid = threadIdx.x;
  const int fl = sniff_flags(W, S, tid, &flags_sh);
  const bool s_bf = (fl & 2) != 0;
  const int tb = blockIdx.x;  // t-byte index: t = tb*8 + bit
  unsigned wrd[4] = {0u, 0u, 0u, 0u};
#pragma unroll
  for (int kk = 0; kk < 16; ++kk) {
    const int k = tid * 16 + kk;
    unsigned byte = 0;
    if (s_bf) {
      const unsigned short* Sb = (const unsigned short*)S;
      const uint4 u = *(const uint4*)&Sb[(size_t)k * SEQ_LEN + tb * 8];
      byte |= (((u.x & 0x7FFFu) != 0u) ? 1u : 0u) << 0;
      byte |= (((u.x & 0x7FFF0000u) != 0u) ? 1u : 0u) << 1;
      byte |= (((u.y & 0x7FFFu) != 0u) ? 1u : 0u) << 2;
      byte |= (((u.y & 0x7FFF0000u) != 0u) ? 1u : 0u) << 3;
      byte |= (((u.z & 0x7FFFu) != 0u) ? 1u : 0u) << 4;
      byte |= (((u.z & 0x7FFF0000u) != 0u) ? 1u : 0u) << 5;
      byte |= (((u.w & 0x7FFFu) != 0u) ? 1u : 0u) << 6;
      byte |= (((u.w & 0x7FFF0000u) != 0u) ? 1u : 0u) << 7;
    } else {
      const float* Sf = (const float*)S;
      const size_t base = (size_t)k * SEQ_LEN + tb * 8;
      const float4 f0 = *(const float4*)&Sf[base];
      const float4 f1 = *(const float4*)&Sf[base + 4];
      byte |= ((f0.x != 0.0f) ? 1u : 0u) << 0;
      byte |= ((f0.y != 0.0f) ? 1u : 0u) << 1;
      byte |= ((f0.z != 0.0f) ? 1u : 0u) << 2;
      byte |= ((f0.w != 0.0f) ? 1u : 0u) << 3;
      byte |= ((f1.x != 0.0f) ? 1u : 0u) << 4;
      byte |= ((f1.y != 0.0f) ? 1u : 0u) << 5;
      byte |= ((f1.z != 0.0f) ? 1u : 0u) << 6;
      byte |= ((f1.w != 0.0f) ? 1u : 0u) << 7;
    }
    wrd[kk >> 2] |= byte << ((kk & 3) * 8);
  }
  *(uint4*)&MT[(size_t)tb * N_PRE + tid * 16] =
      make_uint4(wrd[0], wrd[1], wrd[2], wrd[3]);
}

// ---------------- list build: MT -> per-t ascending spike list --------------
__global__ __launch_bounds__(64) void snn_list_build(const unsigned char* __restrict__ MT,
                                                     unsigned short* __restrict__ lists,
                                                     int* __restrict__ lens,
                                                     int* __restrict__ splits) {
  const int t = blockIdx.x;
  const int l = threadIdx.x;
  const unsigned char* Mrow = MT + (size_t)(t >> 3) * N_PRE;
  const int bit = t & 7;
  unsigned short* Lp = lists + (size_t)t * N_PRE;
  int base = 0;
  int split = 0;
#pragma unroll
  for (int c = 0; c < 16; ++c) {
    const int k = c * 64 + l;
    const int b = (Mrow[k] >> bit) & 1;
    const unsigned long long m = __ballot(b != 0);
    const int pre = __popcll(m & ((1ull << l) - 1ull));
    if (b) Lp[base + pre] = (unsigned short)k;
    base += __popcll(m);
    if (c == 7) split = base;
  }
  if (l == 0) {
    lens[t] = base;
    splits[t] = split;
  }
}

// ---------------- sparse GEMM: C[t][n] = sum over spiking k of WT[k][n] -----
// block = (t, n-half 1024); 256 thr x float4. 8-wide batched list walk:
// one uint4 = 8 u16 entries -> 8 independent WT loads in flight -> adds in
// ascending list order (bit-identical chain).
__global__ __launch_bounds__(256) void snn_gemm_sp(const float* __restrict__ WT,
                                                   const unsigned short* __restrict__ lists,
                                                   const int* __restrict__ lens,
                                                   const int* __restrict__ splits,
                                                   float* __restrict__ C,
                                                   int t0, int ct) {
  const int tl = blockIdx.x;
  const int tg = t0 + tl;
  const int n = (int)blockIdx.y * 1024 + (int)threadIdx.x * 4;
  const unsigned short* __restrict__ L = lists + (size_t)tg * N_PRE;
  const int len = lens[tg];
  const int sp = splits[tg];
  float a0 = 0.f, a1 = 0.f, a2 = 0.f, a3 = 0.f;  // active chain accumulator
  float lo0, lo1, lo2, lo3;

#define SP_ADD(K)                                                      \
  {                                                                    \
    const float4 w = *(const float4*)&WT[((size_t)(K) << 11) + n];     \
    a0 += w.x; a1 += w.y; a2 += w.z; a3 += w.w;                        \
  }
#define SP_BATCH8(I)                                                   \
  {                                                                    \
    const uint4 u = *(const uint4*)&L[I];                              \
    const int k0 = u.x & 0xFFFF, k1 = u.x >> 16;                       \
    const int k2 = u.y & 0xFFFF, k3 = u.y >> 16;                       \
    const int k4 = u.z & 0xFFFF, k5 = u.z >> 16;                       \
    const int k6 = u.w & 0xFFFF, k7 = u.w >> 16;                       \
    const float4 w0 = *(const float4*)&WT[((size_t)k0 << 11) + n];     \
    const float4 w1 = *(const float4*)&WT[((size_t)k1 << 11) + n];     \
    const float4 w2 = *(const float4*)&WT[((size_t)k2 << 11) + n];     \
    const float4 w3 = *(const float4*)&WT[((size_t)k3 << 11) + n];     \
    const float4 w4 = *(const float4*)&WT[((size_t)k4 << 11) + n];     \
    const float4 w5 = *(const float4*)&WT[((size_t)k5 << 11) + n];     \
    const float4 w6 = *(const float4*)&WT[((size_t)k6 << 11) + n];     \
    const float4 w7 = *(const float4*)&WT[((size_t)k7 << 11) + n];     \
    a0 += w0.x; a1 += w0.y; a2 += w0.z; a3 += w0.w;                    \
    a0 += w1.x; a1 += w1.y; a2 += w1.z; a3 += w1.w;                    \
    a0 += w2.x; a1 += w2.y; a2 += w2.z; a3 += w2.w;                    \
    a0 += w3.x; a1 += w3.y; a2 += w3.z; a3 += w3.w;                    \
    a0 += w4.x; a1 += w4.y; a2 += w4.z; a3 += w4.w;                    \
    a0 += w5.x; a1 += w5.y; a2 += w5.z; a3 += w5.w;                    \
    a0 += w6.x; a1 += w6.y; a2 += w6.z; a3 += w6.w;                    \
    a0 += w7.x; a1 += w7.y; a2 += w7.z; a3 += w7.w;                    \
  }

  int i = 0;
  // ---- lo chain: k in [0, 512), list-ascending ----
  for (; i + 8 <= sp; i += 8) SP_BATCH8(i)
  for (; i < sp; ++i) SP_ADD(L[i])
  lo0 = a0; lo1 = a1; lo2 = a2; lo3 = a3;
  a0 = a1 = a2 = a3 = 0.f;
  // ---- hi chain: k in [512, 1024), list-ascending ----
  for (; i < len && (i & 7) != 0; ++i) SP_ADD(L[i])
  for (; i + 8 <= len; i += 8) SP_BATCH8(i)
  for (; i < len; ++i) SP_ADD(L[i])
#undef SP_BATCH8
#undef SP_ADD

  *(float4*)&C[(size_t)tl * N_POST + n] =
      make_float4(lo0 + a0, lo1 + a1, lo2 + a2, lo3 + a3);  // rn(S1+S2)
}

// ---------------- Scan phase 1: checkpoint chain (32 waves) -----------------
// v9: full-tile prefetch. Holds current 64-t tile in cur[64]; issues ALL 64
// next-tile loads spread across the 4 chain groups (64 independent loads in
// flight, 256-1024 cyc cover each vs ~900 cyc C-load latency). Chain ops
// and order identical to emit -> bitwise-equal v.
__global__ __launch_bounds__(64) void snn_scan_chk(const float* __restrict__ C,
                                                   float* __restrict__ vchk,
                                                   float* __restrict__ v_carry,
                                                   int ct, int first) {
  const int l = threadIdx.x;
  const int n = blockIdx.x * 64 + l;
  float v = 0.0f;
  if (!first) v = v_carry[n];
  const int ntiles = ct / 64;

  float cur[64], nxt[64];
#pragma unroll
  for (int j = 0; j < 64; ++j) cur[j] = C[(size_t)j * N_POST + n];

  for (int tile = 0; tile < ntiles; ++tile) {
    vchk[(size_t)tile * N_POST + n] = v;  // carry-in for this tile
    const int nb = (tile + 1) * 64;
    const bool hn = (tile + 1 < ntiles);
#pragma unroll
    for (int g = 0; g < 4; ++g) {
      // issue next-tile group g loads (independent of chain; 64 in flight
      // by end of tile, each covered by >=1 group of chain latency)
      if (hn) {
#pragma unroll
        for (int j = 0; j < 16; ++j)
          nxt[g * 16 + j] = C[(size_t)(nb + g * 16 + j) * N_POST + n];
      }
      // chain: 16 dependent LIF steps (DO NOT REORDER; identical to emit)
#pragma unroll
      for (int j = 0; j < 16; ++j) {
        const float c = cur[g * 16 + j];
        const float leak = opaque(v * 0.9f);  // rn(v*0.9f)
        v = leak + c;                         // rn(+c)
        const bool fired = (v >= 1.0f);
        v = fired ? 0.0f : v;
      }
    }
#pragma unroll
    for (int j = 0; j < 64; ++j) cur[j] = nxt[j];
  }
  v_carry[n] = v;
}

// ---------------- Scan phase 2: replay + emit (full chip) -------------------
// Block (n-group, tile): 1 wave, replays the 64-step chain from vchk with
// IDENTICAL ops/order (bitwise-equal s,v), stages in LDS [t][65]
// (chain writes bank (t+l)%32 conflict-free; flush reads 2-way = free),
// emits float4-wide on t. 2048 blocks -> full chip for the 64 MB of stores.
__global__ __launch_bounds__(64) void snn_scan_emit(const float* __restrict__ C,
                                                    const float* __restrict__ vchk,
                                                    float* __restrict__ spk,
                                                    float* __restrict__ vout,
                                                    int t0, int ct) {
  __shared__ float sb[64][65];
  __shared__ float vb[64][65];
  const int l = threadIdx.x;
  const int n0 = blockIdx.x * 64;
  const int tile = blockIdx.y;
  const int n = n0 + l;
  const int tb = tile * 64;

  float v = vchk[(size_t)tile * N_POST + n];

  float ccur[16], cnxt[16];
#pragma unroll
  for (int j = 0; j < 16; ++j) ccur[j] = C[(size_t)(tb + j) * N_POST + n];

#pragma unroll
  for (int g = 0; g < 4; ++g) {
    if (g < 3) {
#pragma unroll
      for (int j = 0; j < 16; ++j)
        cnxt[j] = C[(size_t)(tb + (g + 1) * 16 + j) * N_POST + n];
    }
    // chain: 16 dependent LIF steps (DO NOT REORDER; identical to chk)
#pragma unroll
    for (int j = 0; j < 16; ++j) {
      const float c = ccur[j];
      const float leak = opaque(v * 0.9f);  // rn(v*0.9f)
      v = leak + c;                         // rn(+c)
      const bool fired = (v >= 1.0f);
      sb[g * 16 + j][l] = fired ? 1.0f : 0.0f;
      v = fired ? 0.0f : v;
      vb[g * 16 + j][l] = v;
    }
#pragma unroll
    for (int j = 0; j < 16; ++j) ccur[j] = cnxt[j];
  }

  // flush: 16 iters x (4 rows x 16 lanes x float4-on-t); single wave =>
  // program order makes LDS writes visible, no barrier needed.
  const int t4 = (l & 15) * 4;
  const int rq = l >> 4;
  const size_t gtb = (size_t)t0 + tb;
#pragma unroll
  for (int it = 0; it < 16; ++it) {
    const int r = it * 4 + rq;  // neuron row within group
    float4 so, vo;
    so.x = sb[t4 + 0][r]; so.y = sb[t4 + 1][r];
    so.z = sb[t4 + 2][r]; so.w = sb[t4 + 3][r];
    vo.x = vb[t4 + 0][r]; vo.y = vb[t4 + 1][r];
    vo.z = vb[t4 + 2][r]; vo.w = vb[t4 + 3][r];
    const size_t go = (size_t)(n0 + r) * SEQ_LEN + gtb + t4;
    *(float4*)&spk[go] = so;
    *(float4*)&vout[go] = vo;
  }
}

// ---------------- fused fallback (ws too small), same [512|512] chain -------
__global__ __launch_bounds__(256) void snn_fused_blis(const void* __restrict__ W,
                                                      const void* __restrict__ S,
                                                      float* __restrict__ spk,
                                                      float* __restrict__ vout) {
  __shared__ float As[16][68];
  __shared__ float Bs[16][68];
  __shared__ float Ct[64][65];
  __shared__ float vsh[64];
  __shared__ int flags_sh;
  const int tid = threadIdx.x;
  const int fl = sniff_flags(W, S, tid, &flags_sh);
  const bool w_bf = (fl & 1) != 0;
  const bool s_bf = (fl & 2) != 0;

  const int tx = tid & 15;
  const int ty = tid >> 4;
  const int m0 = blockIdx.x * 64;
  if (tid < 64) vsh[tid] = 0.0f;

  for (int t0 = 0; t0 < SEQ_LEN; t0 += 64) {
    float acc0[4][4] = {{0.f}};
    float acc1[4][4] = {{0.f}};
    int k0 = 0;
#define FUSED_SEGMENT(ACC, KEND)                                                 \
    for (; k0 < (KEND); k0 += 16) {                                              \
      {                                                                          \
        const int r = tid >> 4, c = tid & 15;                                    \
        _Pragma("unroll") for (int j = 0; j < 4; ++j)                            \
            As[c][r + 16 * j] =                                                  \
                load_dyn(W, (size_t)(m0 + r + 16 * j) * N_PRE + k0 + c, w_bf);   \
      }                                                                          \
      {                                                                          \
        const int r = tid >> 6, c = tid & 63;                                    \
        _Pragma("unroll") for (int j = 0; j < 4; ++j)                            \
            Bs[r + 4 * j][c] =                                                   \
                load_dyn(S, (size_t)(k0 + r + 4 * j) * SEQ_LEN + t0 + c, s_bf);  \
      }                                                                          \
      __syncthreads();                                                           \
      _Pragma("unroll") for (int k = 0; k < 16; ++k) {                           \
        _Pragma("unroll") for (int i = 0; i < 4; ++i)                            \
            _Pragma("unroll") for (int j = 0; j < 4; ++j)                        \
                ACC[i][j] += As[k][ty * 4 + i] * Bs[k][tx * 4 + j];              \
      }                                                                          \
      __syncthreads();                                                           \
    }

    FUSED_SEGMENT(acc0, KSPLIT)
    FUSED_SEGMENT(acc1, N_PRE)
#undef FUSED_SEGMENT

#pragma unroll
    for (int i = 0; i < 4; ++i)
#pragma unroll
      for (int j = 0; j < 4; ++j) Ct[ty * 4 + i][tx * 4 + j] = acc0[i][j] + acc1[i][j];
    __syncthreads();
    if (tid < 64) {
      float v = vsh[tid];
#pragma unroll
      for (int k = 0; k < 64; ++k) {
        const float leak = opaque(v * 0.9f);
        v = leak + Ct[tid][k];
        const bool fired = (v >= 1.0f);
        const size_t g = (size_t)(m0 + tid) * SEQ_LEN + t0 + k;
        spk[g] = fired ? 1.0f : 0.0f;
        v = fired ? 0.0f : v;
        vout[g] = v;
      }
      vsh[tid] = v;
    }
    __syncthreads();
  }
}

extern "C" void kernel_launch(void* const* d_in, const int* in_sizes, int n_in,
                              void* d_out, int out_size, void* d_ws, size_t ws_size,
                              hipStream_t stream) {
  const void* stim = d_in[0];
  const void* weights = d_in[1];
  if (n_in >= 2 && in_sizes[0] == N_POST * N_PRE && in_sizes[1] == N_PRE * SEQ_LEN) {
    weights = d_in[0];
    stim = d_in[1];
  }

  float* spk = (float*)d_out;                    // output 0: spikes [N_POST, SEQ_LEN]
  float* vout = spk + (size_t)N_POST * SEQ_LEN;  // output 1: v      [N_POST, SEQ_LEN]

  // ---- workspace carve ----
  char* p = (char*)d_ws;
  float* WT = (float*)p;                 p += (size_t)N_PRE * N_POST * 4;      // 8 MB
  unsigned char* MT = (unsigned char*)p; p += (size_t)(SEQ_LEN / 8) * N_PRE;   // 512 KB
  unsigned short* lists = (unsigned short*)p; p += (size_t)SEQ_LEN * N_PRE * 2;// 8 MB
  int* lens = (int*)p;                   p += (size_t)SEQ_LEN * 4;             // 16 KB
  int* splits = (int*)p;                 p += (size_t)SEQ_LEN * 4;             // 16 KB
  float* v_carry = (float*)p;            p += (size_t)N_POST * 4;              // 8 KB
  float* vchk = (float*)p;               p += (size_t)(SEQ_LEN / 64) * N_POST * 4;  // 512 KB
  float* C = (float*)p;
  const size_t used = (size_t)(p - (char*)d_ws);
  const size_t remain = (ws_size > used) ? (ws_size - used) : 0;

  int chunkT = (int)((remain / ((size_t)N_POST * sizeof(float))) / 64 * 64);
  if (chunkT > SEQ_LEN) chunkT = SEQ_LEN;
  if (chunkT >= 64) {  // round to power of two so chunkT divides SEQ_LEN
    int pw = 64;
    while (pw * 2 <= chunkT && pw < SEQ_LEN) pw *= 2;
    chunkT = pw;
  }

  if (chunkT >= 64) {
    snn_wt_build<<<dim3(N_PRE / 64, N_POST / 64), dim3(256), 0, stream>>>(weights, stim, WT);
    snn_mask_build<<<dim3(SEQ_LEN / 8), dim3(64), 0, stream>>>(weights, stim, MT);
    snn_list_build<<<dim3(SEQ_LEN), dim3(64), 0, stream>>>(MT, lists, lens, splits);
    for (int t0 = 0; t0 < SEQ_LEN; t0 += chunkT) {
      const int ct = (SEQ_LEN - t0 < chunkT) ? (SEQ_LEN - t0) : chunkT;  // mult of 64
      snn_gemm_sp<<<dim3(ct, 2), dim3(256), 0, stream>>>(WT, lists, lens, splits, C, t0, ct);
      snn_scan_chk<<<dim3(N_POST / 64), dim3(64), 0, stream>>>(C, vchk, v_carry,
                                                               ct, t0 == 0);
      snn_scan_emit<<<dim3(N_POST / 64, ct / 64), dim3(64), 0, stream>>>(C, vchk, spk,
                                                                         vout, t0, ct);
    }
  } else {
    snn_fused_blis<<<dim3(N_POST / 64), dim3(256), 0, stream>>>(weights, stim, spk, vout);
  }
}

// Round 11
// 349.069 us; speedup vs baseline: 1.6166x; 1.0397x over previous
//
#include <hip/hip_runtime.h>

#define N_PRE 1024
#define N_POST 2048
#define SEQ_LEN 4096

// Reference-verified numerics (R11 PASS): per C element two fp32 segment
// chains k in [0,512) and [512,1024), ascending, single accumulator each,
// combined rn(S1+S2). stim in {0,1} -> products exact -> FMA == mul+add.
// Scan: v = rn(rn(v*0.9f) + c), fire >= 1.0f, reset 0. DO NOT REORDER.
//
// Sparse (v6, PASS absmax 0.015625): skipping adds of exact +/-0.0 is
// BIT-IDENTICAL (acc starts +0.0; RN never yields -0.0 from a sum, so
// rn(acc + ±0) == acc). Walk the ascending per-t spike list: lo-chain k<512,
// hi-chain k>=512, write rn(lo+hi).
//
// v10 FAILED post-timing replay (absmax 1.0): __builtin_nontemporal_store on
// C bypassed L2 coherence -> next kernel read stale/poisoned lines on graph
// replay. LESSON: no nt stores on buffers a later kernel reads.
// v11 = v10 minus nt store: XCD-slice pinning kept (64-thr blocks own a
// 256-n slice; slice = blockIdx.x & 7 -> round-robin puts slice i on XCD i,
// 1MB L2-resident WT slice), plain coherent float4 C stores.
#define KSPLIT 512

__device__ __forceinline__ float opaque(float x) {
  asm volatile("" : "+v"(x));
  return x;
}

__device__ __forceinline__ float load_dyn(const void* p, size_t idx, bool isbf) {
  if (isbf) {
    const unsigned short b = ((const unsigned short*)p)[idx];
    return __uint_as_float(((unsigned int)b) << 16);
  }
  return ((const float*)p)[idx];
}

// Input-dtype sniff (established: weights fp32, stim bf16; kept for safety).
__device__ __forceinline__ int sniff_flags(const void* W, const void* S, int tid,
                                           int* flags_sh) {
  if (tid < 64) {
    const unsigned short* uw = (const unsigned short*)W;
    const float f = fabsf(__uint_as_float(((unsigned int)uw[tid * 2]) << 16));
    const bool big = !(f < 64.f);
    const unsigned long long wb = __ballot(big);
    const unsigned short* us = (const unsigned short*)S;
    int hit = 0;
    for (int j = 0; j < 64; ++j) hit |= (us[tid * 128 + 2 * j] == 0x3F80u) ? 1 : 0;
    const unsigned long long sb = __ballot(hit != 0);
    if (tid == 0) *flags_sh = ((wb == 0ull) ? 1 : 0) | ((sb != 0ull) ? 2 : 0);
  }
  __syncthreads();
  return *flags_sh;
}

// ---------------- WT build: W[n][k] -> WT[k][n] (fp32), LDS transpose -------
__global__ __launch_bounds__(256) void snn_wt_build(const void* __restrict__ W,
                                                    const void* __restrict__ S,
                                                    float* __restrict__ WT) {
  __shared__ float tile[64][65];
  __shared__ int flags_sh;
  const int tid = threadIdx.x;
  const int fl = sniff_flags(W, S, tid, &flags_sh);
  const bool w_bf = (fl & 1) != 0;
  const int k0 = blockIdx.x * 64;
  const int nn0 = blockIdx.y * 64;
  {
    const int r = tid >> 2;
    const int cq = tid & 3;
    if (!w_bf) {
      const float* Wf = (const float*)W;
#pragma unroll
      for (int p = 0; p < 4; ++p) {
        const int c = cq * 16 + p * 4;
        const float4 va = *(const float4*)&Wf[(size_t)(nn0 + r) * N_PRE + k0 + c];
        tile[c + 0][r] = va.x; tile[c + 1][r] = va.y;
        tile[c + 2][r] = va.z; tile[c + 3][r] = va.w;
      }
    } else {
#pragma unroll
      for (int p = 0; p < 4; ++p)
#pragma unroll
        for (int j = 0; j < 4; ++j) {
          const int c = cq * 16 + p * 4 + j;
          tile[c][r] = load_dyn(W, (size_t)(nn0 + r) * N_PRE + k0 + c, true);
        }
    }
  }
  __syncthreads();
  {
    const int kr = tid >> 2;
    const int nq = tid & 3;
#pragma unroll
    for (int p = 0; p < 4; ++p) {
      const int c = nq * 16 + p * 4;
      float4 o;
      o.x = tile[kr][c + 0]; o.y = tile[kr][c + 1];
      o.z = tile[kr][c + 2]; o.w = tile[kr][c + 3];
      *(float4*)&WT[(size_t)(k0 + kr) * N_POST + nn0 + c] = o;
    }
  }
}

// ---------------- mask build: stim -> MT[t/8][k] bitmask bytes --------------
__global__ __launch_bounds__(64) void snn_mask_build(const void* __restrict__ W,
                                                     const void* __restrict__ S,
                                                     unsigned char* __restrict__ MT) {
  __shared__ int flags_sh;
  const int tid = threadIdx.x;
  const int fl = sniff_flags(W, S, tid, &flags_sh);
  const bool s_bf = (fl & 2) != 0;
  const int tb = blockIdx.x;  // t-byte index: t = tb*8 + bit
  unsigned wrd[4] = {0u, 0u, 0u, 0u};
#pragma unroll
  for (int kk = 0; kk < 16; ++kk) {
    const int k = tid * 16 + kk;
    unsigned byte = 0;
    if (s_bf) {
      const unsigned short* Sb = (const unsigned short*)S;
      const uint4 u = *(const uint4*)&Sb[(size_t)k * SEQ_LEN + tb * 8];
      byte |= (((u.x & 0x7FFFu) != 0u) ? 1u : 0u) << 0;
      byte |= (((u.x & 0x7FFF0000u) != 0u) ? 1u : 0u) << 1;
      byte |= (((u.y & 0x7FFFu) != 0u) ? 1u : 0u) << 2;
      byte |= (((u.y & 0x7FFF0000u) != 0u) ? 1u : 0u) << 3;
      byte |= (((u.z & 0x7FFFu) != 0u) ? 1u : 0u) << 4;
      byte |= (((u.z & 0x7FFF0000u) != 0u) ? 1u : 0u) << 5;
      byte |= (((u.w & 0x7FFFu) != 0u) ? 1u : 0u) << 6;
      byte |= (((u.w & 0x7FFF0000u) != 0u) ? 1u : 0u) << 7;
    } else {
      const float* Sf = (const float*)S;
      const size_t base = (size_t)k * SEQ_LEN + tb * 8;
      const float4 f0 = *(const float4*)&Sf[base];
      const float4 f1 = *(const float4*)&Sf[base + 4];
      byte |= ((f0.x != 0.0f) ? 1u : 0u) << 0;
      byte |= ((f0.y != 0.0f) ? 1u : 0u) << 1;
      byte |= ((f0.z != 0.0f) ? 1u : 0u) << 2;
      byte |= ((f0.w != 0.0f) ? 1u : 0u) << 3;
      byte |= ((f1.x != 0.0f) ? 1u : 0u) << 4;
      byte |= ((f1.y != 0.0f) ? 1u : 0u) << 5;
      byte |= ((f1.z != 0.0f) ? 1u : 0u) << 6;
      byte |= ((f1.w != 0.0f) ? 1u : 0u) << 7;
    }
    wrd[kk >> 2] |= byte << ((kk & 3) * 8);
  }
  *(uint4*)&MT[(size_t)tb * N_PRE + tid * 16] =
      make_uint4(wrd[0], wrd[1], wrd[2], wrd[3]);
}

// ---------------- list build: MT -> per-t ascending spike list --------------
__global__ __launch_bounds__(64) void snn_list_build(const unsigned char* __restrict__ MT,
                                                     unsigned short* __restrict__ lists,
                                                     int* __restrict__ lens,
                                                     int* __restrict__ splits) {
  const int t = blockIdx.x;
  const int l = threadIdx.x;
  const unsigned char* Mrow = MT + (size_t)(t >> 3) * N_PRE;
  const int bit = t & 7;
  unsigned short* Lp = lists + (size_t)t * N_PRE;
  int base = 0;
  int split = 0;
#pragma unroll
  for (int c = 0; c < 16; ++c) {
    const int k = c * 64 + l;
    const int b = (Mrow[k] >> bit) & 1;
    const unsigned long long m = __ballot(b != 0);
    const int pre = __popcll(m & ((1ull << l) - 1ull));
    if (b) Lp[base + pre] = (unsigned short)k;
    base += __popcll(m);
    if (c == 7) split = base;
  }
  if (l == 0) {
    lens[t] = base;
    splits[t] = split;
  }
}

// ---------------- sparse GEMM: C[t][n] = sum over spiking k of WT[k][n] -----
// v11: XCD-slice pinning (64 thr x float4 = 256-n slice; slice = bid & 7 ->
// round-robin puts slice i on XCD i only -> 1MB L2-resident WT slice).
// 8-wide batched list walk, adds in ascending list order (bit-identical).
// Plain coherent float4 C store (v10's nt store raced on graph replay).
__global__ __launch_bounds__(64) void snn_gemm_sp(const float* __restrict__ WT,
                                                  const unsigned short* __restrict__ lists,
                                                  const int* __restrict__ lens,
                                                  const int* __restrict__ splits,
                                                  float* __restrict__ C,
                                                  int t0, int ct) {
  const int slice = (int)blockIdx.x & 7;
  const int tl = (int)blockIdx.x >> 3;
  const int tg = t0 + tl;
  const int n = slice * 256 + (int)threadIdx.x * 4;
  const unsigned short* __restrict__ L = lists + (size_t)tg * N_PRE;
  const int len = lens[tg];
  const int sp = splits[tg];
  float a0 = 0.f, a1 = 0.f, a2 = 0.f, a3 = 0.f;  // active chain accumulator
  float lo0, lo1, lo2, lo3;

#define SP_ADD(K)                                                      \
  {                                                                    \
    const float4 w = *(const float4*)&WT[((size_t)(K) << 11) + n];     \
    a0 += w.x; a1 += w.y; a2 += w.z; a3 += w.w;                        \
  }
#define SP_BATCH8(I)                                                   \
  {                                                                    \
    const uint4 u = *(const uint4*)&L[I];                              \
    const int k0 = u.x & 0xFFFF, k1 = u.x >> 16;                       \
    const int k2 = u.y & 0xFFFF, k3 = u.y >> 16;                       \
    const int k4 = u.z & 0xFFFF, k5 = u.z >> 16;                       \
    const int k6 = u.w & 0xFFFF, k7 = u.w >> 16;                       \
    const float4 w0 = *(const float4*)&WT[((size_t)k0 << 11) + n];     \
    const float4 w1 = *(const float4*)&WT[((size_t)k1 << 11) + n];     \
    const float4 w2 = *(const float4*)&WT[((size_t)k2 << 11) + n];     \
    const float4 w3 = *(const float4*)&WT[((size_t)k3 << 11) + n];     \
    const float4 w4 = *(const float4*)&WT[((size_t)k4 << 11) + n];     \
    const float4 w5 = *(const float4*)&WT[((size_t)k5 << 11) + n];     \
    const float4 w6 = *(const float4*)&WT[((size_t)k6 << 11) + n];     \
    const float4 w7 = *(const float4*)&WT[((size_t)k7 << 11) + n];     \
    a0 += w0.x; a1 += w0.y; a2 += w0.z; a3 += w0.w;                    \
    a0 += w1.x; a1 += w1.y; a2 += w1.z; a3 += w1.w;                    \
    a0 += w2.x; a1 += w2.y; a2 += w2.z; a3 += w2.w;                    \
    a0 += w3.x; a1 += w3.y; a2 += w3.z; a3 += w3.w;                    \
    a0 += w4.x; a1 += w4.y; a2 += w4.z; a3 += w4.w;                    \
    a0 += w5.x; a1 += w5.y; a2 += w5.z; a3 += w5.w;                    \
    a0 += w6.x; a1 += w6.y; a2 += w6.z; a3 += w6.w;                    \
    a0 += w7.x; a1 += w7.y; a2 += w7.z; a3 += w7.w;                    \
  }

  int i = 0;
  // ---- lo chain: k in [0, 512), list-ascending ----
  for (; i + 8 <= sp; i += 8) SP_BATCH8(i)
  for (; i < sp; ++i) SP_ADD(L[i])
  lo0 = a0; lo1 = a1; lo2 = a2; lo3 = a3;
  a0 = a1 = a2 = a3 = 0.f;
  // ---- hi chain: k in [512, 1024), list-ascending ----
  for (; i < len && (i & 7) != 0; ++i) SP_ADD(L[i])
  for (; i + 8 <= len; i += 8) SP_BATCH8(i)
  for (; i < len; ++i) SP_ADD(L[i])
#undef SP_BATCH8
#undef SP_ADD

  *(float4*)&C[(size_t)tl * N_POST + n] =
      make_float4(lo0 + a0, lo1 + a1, lo2 + a2, lo3 + a3);  // rn(S1+S2)
}

// ---------------- Scan phase 1: checkpoint chain (32 waves) -----------------
// v9: full-tile prefetch (64 loads in flight, verified: 158 -> off top-5).
// Chain ops and order identical to emit -> bitwise-equal v.
__global__ __launch_bounds__(64) void snn_scan_chk(const float* __restrict__ C,
                                                   float* __restrict__ vchk,
                                                   float* __restrict__ v_carry,
                                                   int ct, int first) {
  const int l = threadIdx.x;
  const int n = blockIdx.x * 64 + l;
  float v = 0.0f;
  if (!first) v = v_carry[n];
  const int ntiles = ct / 64;

  float cur[64], nxt[64];
#pragma unroll
  for (int j = 0; j < 64; ++j) cur[j] = C[(size_t)j * N_POST + n];

  for (int tile = 0; tile < ntiles; ++tile) {
    vchk[(size_t)tile * N_POST + n] = v;  // carry-in for this tile
    const int nb = (tile + 1) * 64;
    const bool hn = (tile + 1 < ntiles);
#pragma unroll
    for (int g = 0; g < 4; ++g) {
      // issue next-tile group g loads (independent of chain; 64 in flight
      // by end of tile, each covered by >=1 group of chain latency)
      if (hn) {
#pragma unroll
        for (int j = 0; j < 16; ++j)
          nxt[g * 16 + j] = C[(size_t)(nb + g * 16 + j) * N_POST + n];
      }
      // chain: 16 dependent LIF steps (DO NOT REORDER; identical to emit)
#pragma unroll
      for (int j = 0; j < 16; ++j) {
        const float c = cur[g * 16 + j];
        const float leak = opaque(v * 0.9f);  // rn(v*0.9f)
        v = leak + c;                         // rn(+c)
        const bool fired = (v >= 1.0f);
        v = fired ? 0.0f : v;
      }
    }
#pragma unroll
    for (int j = 0; j < 64; ++j) cur[j] = nxt[j];
  }
  v_carry[n] = v;
}

// ---------------- Scan phase 2: replay + emit (full chip) -------------------
// Block (n-group, tile): 1 wave, replays the 64-step chain from vchk with
// IDENTICAL ops/order (bitwise-equal s,v), stages in LDS [t][65]
// (chain writes bank (t+l)%32 conflict-free; flush reads 2-way = free),
// emits float4-wide on t. 2048 blocks -> full chip for the 64 MB of stores.
__global__ __launch_bounds__(64) void snn_scan_emit(const float* __restrict__ C,
                                                    const float* __restrict__ vchk,
                                                    float* __restrict__ spk,
                                                    float* __restrict__ vout,
                                                    int t0, int ct) {
  __shared__ float sb[64][65];
  __shared__ float vb[64][65];
  const int l = threadIdx.x;
  const int n0 = blockIdx.x * 64;
  const int tile = blockIdx.y;
  const int n = n0 + l;
  const int tb = tile * 64;

  float v = vchk[(size_t)tile * N_POST + n];

  float ccur[16], cnxt[16];
#pragma unroll
  for (int j = 0; j < 16; ++j) ccur[j] = C[(size_t)(tb + j) * N_POST + n];

#pragma unroll
  for (int g = 0; g < 4; ++g) {
    if (g < 3) {
#pragma unroll
      for (int j = 0; j < 16; ++j)
        cnxt[j] = C[(size_t)(tb + (g + 1) * 16 + j) * N_POST + n];
    }
    // chain: 16 dependent LIF steps (DO NOT REORDER; identical to chk)
#pragma unroll
    for (int j = 0; j < 16; ++j) {
      const float c = ccur[j];
      const float leak = opaque(v * 0.9f);  // rn(v*0.9f)
      v = leak + c;                         // rn(+c)
      const bool fired = (v >= 1.0f);
      sb[g * 16 + j][l] = fired ? 1.0f : 0.0f;
      v = fired ? 0.0f : v;
      vb[g * 16 + j][l] = v;
    }
#pragma unroll
    for (int j = 0; j < 16; ++j) ccur[j] = cnxt[j];
  }

  // flush: 16 iters x (4 rows x 16 lanes x float4-on-t); single wave =>
  // program order makes LDS writes visible, no barrier needed.
  const int t4 = (l & 15) * 4;
  const int rq = l >> 4;
  const size_t gtb = (size_t)t0 + tb;
#pragma unroll
  for (int it = 0; it < 16; ++it) {
    const int r = it * 4 + rq;  // neuron row within group
    float4 so, vo;
    so.x = sb[t4 + 0][r]; so.y = sb[t4 + 1][r];
    so.z = sb[t4 + 2][r]; so.w = sb[t4 + 3][r];
    vo.x = vb[t4 + 0][r]; vo.y = vb[t4 + 1][r];
    vo.z = vb[t4 + 2][r]; vo.w = vb[t4 + 3][r];
    const size_t go = (size_t)(n0 + r) * SEQ_LEN + gtb + t4;
    *(float4*)&spk[go] = so;
    *(float4*)&vout[go] = vo;
  }
}

// ---------------- fused fallback (ws too small), same [512|512] chain -------
__global__ __launch_bounds__(256) void snn_fused_blis(const void* __restrict__ W,
                                                      const void* __restrict__ S,
                                                      float* __restrict__ spk,
                                                      float* __restrict__ vout) {
  __shared__ float As[16][68];
  __shared__ float Bs[16][68];
  __shared__ float Ct[64][65];
  __shared__ float vsh[64];
  __shared__ int flags_sh;
  const int tid = threadIdx.x;
  const int fl = sniff_flags(W, S, tid, &flags_sh);
  const bool w_bf = (fl & 1) != 0;
  const bool s_bf = (fl & 2) != 0;

  const int tx = tid & 15;
  const int ty = tid >> 4;
  const int m0 = blockIdx.x * 64;
  if (tid < 64) vsh[tid] = 0.0f;

  for (int t0 = 0; t0 < SEQ_LEN; t0 += 64) {
    float acc0[4][4] = {{0.f}};
    float acc1[4][4] = {{0.f}};
    int k0 = 0;
#define FUSED_SEGMENT(ACC, KEND)                                                 \
    for (; k0 < (KEND); k0 += 16) {                                              \
      {                                                                          \
        const int r = tid >> 4, c = tid & 15;                                    \
        _Pragma("unroll") for (int j = 0; j < 4; ++j)                            \
            As[c][r + 16 * j] =                                                  \
                load_dyn(W, (size_t)(m0 + r + 16 * j) * N_PRE + k0 + c, w_bf);   \
      }                                                                          \
      {                                                                          \
        const int r = tid >> 6, c = tid & 63;                                    \
        _Pragma("unroll") for (int j = 0; j < 4; ++j)                            \
            Bs[r + 4 * j][c] =                                                   \
                load_dyn(S, (size_t)(k0 + r + 4 * j) * SEQ_LEN + t0 + c, s_bf);  \
      }                                                                          \
      __syncthreads();                                                           \
      _Pragma("unroll") for (int k = 0; k < 16; ++k) {                           \
        _Pragma("unroll") for (int i = 0; i < 4; ++i)                            \
            _Pragma("unroll") for (int j = 0; j < 4; ++j)                        \
                ACC[i][j] += As[k][ty * 4 + i] * Bs[k][tx * 4 + j];              \
      }                                                                          \
      __syncthreads();                                                           \
    }

    FUSED_SEGMENT(acc0, KSPLIT)
    FUSED_SEGMENT(acc1, N_PRE)
#undef FUSED_SEGMENT

#pragma unroll
    for (int i = 0; i < 4; ++i)
#pragma unroll
      for (int j = 0; j < 4; ++j) Ct[ty * 4 + i][tx * 4 + j] = acc0[i][j] + acc1[i][j];
    __syncthreads();
    if (tid < 64) {
      float v = vsh[tid];
#pragma unroll
      for (int k = 0; k < 64; ++k) {
        const float leak = opaque(v * 0.9f);
        v = leak + Ct[tid][k];
        const bool fired = (v >= 1.0f);
        const size_t g = (size_t)(m0 + tid) * SEQ_LEN + t0 + k;
        spk[g] = fired ? 1.0f : 0.0f;
        v = fired ? 0.0f : v;
        vout[g] = v;
      }
      vsh[tid] = v;
    }
    __syncthreads();
  }
}

extern "C" void kernel_launch(void* const* d_in, const int* in_sizes, int n_in,
                              void* d_out, int out_size, void* d_ws, size_t ws_size,
                              hipStream_t stream) {
  const void* stim = d_in[0];
  const void* weights = d_in[1];
  if (n_in >= 2 && in_sizes[0] == N_POST * N_PRE && in_sizes[1] == N_PRE * SEQ_LEN) {
    weights = d_in[0];
    stim = d_in[1];
  }

  float* spk = (float*)d_out;                    // output 0: spikes [N_POST, SEQ_LEN]
  float* vout = spk + (size_t)N_POST * SEQ_LEN;  // output 1: v      [N_POST, SEQ_LEN]

  // ---- workspace carve ----
  char* p = (char*)d_ws;
  float* WT = (float*)p;                 p += (size_t)N_PRE * N_POST * 4;      // 8 MB
  unsigned char* MT = (unsigned char*)p; p += (size_t)(SEQ_LEN / 8) * N_PRE;   // 512 KB
  unsigned short* lists = (unsigned short*)p; p += (size_t)SEQ_LEN * N_PRE * 2;// 8 MB
  int* lens = (int*)p;                   p += (size_t)SEQ_LEN * 4;             // 16 KB
  int* splits = (int*)p;                 p += (size_t)SEQ_LEN * 4;             // 16 KB
  float* v_carry = (float*)p;            p += (size_t)N_POST * 4;              // 8 KB
  float* vchk = (float*)p;               p += (size_t)(SEQ_LEN / 64) * N_POST * 4;  // 512 KB
  float* C = (float*)p;
  const size_t used = (size_t)(p - (char*)d_ws);
  const size_t remain = (ws_size > used) ? (ws_size - used) : 0;

  int chunkT = (int)((remain / ((size_t)N_POST * sizeof(float))) / 64 * 64);
  if (chunkT > SEQ_LEN) chunkT = SEQ_LEN;
  if (chunkT >= 64) {  // round to power of two so chunkT divides SEQ_LEN
    int pw = 64;
    while (pw * 2 <= chunkT && pw < SEQ_LEN) pw *= 2;
    chunkT = pw;
  }

  if (chunkT >= 64) {
    snn_wt_build<<<dim3(N_PRE / 64, N_POST / 64), dim3(256), 0, stream>>>(weights, stim, WT);
    snn_mask_build<<<dim3(SEQ_LEN / 8), dim3(64), 0, stream>>>(weights, stim, MT);
    snn_list_build<<<dim3(SEQ_LEN), dim3(64), 0, stream>>>(MT, lists, lens, splits);
    for (int t0 = 0; t0 < SEQ_LEN; t0 += chunkT) {
      const int ct = (SEQ_LEN - t0 < chunkT) ? (SEQ_LEN - t0) : chunkT;  // mult of 64
      snn_gemm_sp<<<dim3(ct * 8), dim3(64), 0, stream>>>(WT, lists, lens, splits, C, t0, ct);
      snn_scan_chk<<<dim3(N_POST / 64), dim3(64), 0, stream>>>(C, vchk, v_carry,
                                                               ct, t0 == 0);
      snn_scan_emit<<<dim3(N_POST / 64, ct / 64), dim3(64), 0, stream>>>(C, vchk, spk,
                                                                         vout, t0, ct);
    }
  } else {
    snn_fused_blis<<<dim3(N_POST / 64), dim3(256), 0, stream>>>(weights, stim, spk, vout);
  }
}